// Round 14
// baseline (438.943 us; speedup 1.0000x reference)
//
#include <hip/hip_runtime.h>
#include <cstdint>

namespace {

constexpr int Lq  = 4096;
constexpr int Bq  = 4;
constexpr int H_  = 16;
constexpr int Mrows = Bq * Lq;               // 16384
constexpr int CHK  = 64;
constexpr int NCHK = Lq / CHK;               // 64
constexpr int QKVS = 3072;                   // fused q|k|v|gate row stride
constexpr float kScale = 0.17677669529663687f;  // 32^-0.5
constexpr float kEps   = 1e-5f;

typedef __attribute__((ext_vector_type(8))) short short8;
typedef __attribute__((ext_vector_type(4))) float f32x4;

__device__ __forceinline__ float bf2f(unsigned short u) {
  return __uint_as_float(((unsigned)u) << 16);
}
__device__ __forceinline__ unsigned short f2bf(float f) {
  unsigned u = __float_as_uint(f);
  u += 0x7fffu + ((u >> 16) & 1u);   // RNE
  return (unsigned short)(u >> 16);
}
__device__ __forceinline__ void gload_lds16(const void* g, void* l) {
  __builtin_amdgcn_global_load_lds(
      (const __attribute__((address_space(1))) void*)g,
      (__attribute__((address_space(3))) void*)l, 16, 0, 0);
}

// ---------- x fp32 -> bf16 ----------
__global__ __launch_bounds__(256)
void cvt_bf16(const float* __restrict__ in, unsigned short* __restrict__ out, int n4)
{
  int i = blockIdx.x * 256 + threadIdx.x;
  const int stride = gridDim.x * 256;
  for (; i < n4; i += stride) {
    float4 f = ((const float4*)in)[i];
    ushort4 u = make_ushort4(f2bf(f.x), f2bf(f.y), f2bf(f.z), f2bf(f.w));
    ((ushort4*)out)[i] = u;
  }
}

// ---------- W[K,N] fp32 -> Wt[N,K] bf16 (optionally scaled) ----------
__global__ __launch_bounds__(256)
void cvt_w_t(const float* __restrict__ W, unsigned short* __restrict__ Wt,
             int K, int N, float scale)
{
  __shared__ float T[64][65];
  const int tid = threadIdx.x;
  const int n0 = blockIdx.x * 64, k0 = blockIdx.y * 64;
  #pragma unroll
  for (int it = 0; it < 4; ++it) {
    int kr = (tid >> 4) + it * 16;
    float4 f = *(const float4*)(W + (size_t)(k0 + kr) * N + n0 + (tid & 15) * 4);
    T[kr][(tid & 15) * 4 + 0] = f.x;
    T[kr][(tid & 15) * 4 + 1] = f.y;
    T[kr][(tid & 15) * 4 + 2] = f.z;
    T[kr][(tid & 15) * 4 + 3] = f.w;
  }
  __syncthreads();
  #pragma unroll
  for (int it = 0; it < 4; ++it) {
    int nr = (tid >> 4) + it * 16;
    int c0 = (tid & 15) * 4;
    ushort4 u = make_ushort4(f2bf(T[c0 + 0][nr] * scale), f2bf(T[c0 + 1][nr] * scale),
                             f2bf(T[c0 + 2][nr] * scale), f2bf(T[c0 + 3][nr] * scale));
    *(ushort4*)(Wt + (size_t)(n0 + nr) * K + k0 + c0) = u;
  }
}

// ========== 256x256 8-wave bf16 GEMM, K=1024, 1 barrier/K-tile ==========
// (R11 verified best: 157 us @ N=3072.) Per K-tile: {vmcnt(0); barrier;
// issue 8 next-tile loads} then 2 K-half phases of {12 ds_read (each
// fragment ONCE) -> lgkmcnt(0) -> 32 MFMA}. No intra-tile barriers.
// EPI: 2 = silu(x+bias[col-2048]) for col>=2048, store bf16
//      3 = plain, store fp32
template<int EPI>
__global__ __launch_bounds__(512, 1)
void gemm256(const unsigned short* __restrict__ A,
             const unsigned short* __restrict__ Bt,
             const float* __restrict__ bias,
             void* __restrict__ Cout, int N)
{
  __shared__ __align__(16) unsigned short As[2][256 * 64];
  __shared__ __align__(16) unsigned short Bs[2][256 * 64];
  const int tid = threadIdx.x;
  const int w = tid >> 6, l = tid & 63;
  const int wm = w >> 2, wn = w & 3;

  const int nbx = gridDim.x;
  const int bid = blockIdx.y * nbx + blockIdx.x;
  const int xcd = bid & 7;
  const int idx = bid >> 3;
  const int nsup = idx >> 4;           // 16 = 8 mPanels * 2 ni
  const int rem = idx & 15;
  const int mi = rem >> 1, ni = rem & 1;
  const int m0 = (xcd * 8 + mi) * 256;
  const int n0 = (nsup * 2 + ni) * 256;

  const int srow = tid >> 3;
  const int scol = ((tid & 7) ^ ((tid >> 3) & 7)) * 8;
  const unsigned short* gAp[4];
  const unsigned short* gBp[4];
  #pragma unroll
  for (int i = 0; i < 4; ++i) {
    gAp[i] = A  + (size_t)(m0 + i * 64 + srow) * 1024 + scol;
    gBp[i] = Bt + (size_t)(n0 + i * 64 + srow) * 1024 + scol;
  }

  const int rbA = wm * 128 + (l & 15);
  const int rbB = wn * 64 + (l & 15);
  const int swzA = (rbA & 7) << 4;
  const int swzB = (rbB & 7) << 4;
  const int colb = (l >> 4) * 16;

  f32x4 acc[8][4];
  #pragma unroll
  for (int i = 0; i < 8; ++i)
    #pragma unroll
    for (int j = 0; j < 4; ++j)
      acc[i][j] = (f32x4){0.f, 0.f, 0.f, 0.f};

  // prologue: stage tile 0 into buf 0
  #pragma unroll
  for (int i = 0; i < 4; ++i) {
    gload_lds16(gAp[i], (char*)&As[0][0] + i * 8192 + w * 1024);
    gload_lds16(gBp[i], (char*)&Bs[0][0] + i * 8192 + w * 1024);
    gAp[i] += 64; gBp[i] += 64;
  }

  int cur = 0;
  for (int t = 0; t < 16; ++t) {
    char* ldsA  = (char*)&As[cur][0];
    char* ldsB  = (char*)&Bs[cur][0];
    char* ldsAn = (char*)&As[cur ^ 1][0];
    char* ldsBn = (char*)&Bs[cur ^ 1][0];

    asm volatile("s_waitcnt vmcnt(0)" ::: "memory");
    __builtin_amdgcn_s_barrier();
    __builtin_amdgcn_sched_barrier(0);
    if (t < 15) {
      #pragma unroll
      for (int i = 0; i < 4; ++i) {
        gload_lds16(gAp[i], ldsAn + i * 8192 + w * 1024);
        gload_lds16(gBp[i], ldsBn + i * 8192 + w * 1024);
        gAp[i] += 64; gBp[i] += 64;
      }
    }

    #pragma unroll
    for (int ks = 0; ks < 2; ++ks) {
      short8 av[8], bv[4];
      #pragma unroll
      for (int mf = 0; mf < 8; ++mf) {
        int row = rbA + mf * 16;
        av[mf] = *(const short8*)(ldsA + row * 128 + ((ks * 64 + colb) ^ swzA));
      }
      #pragma unroll
      for (int nf = 0; nf < 4; ++nf) {
        int row = rbB + nf * 16;
        bv[nf] = *(const short8*)(ldsB + row * 128 + ((ks * 64 + colb) ^ swzB));
      }
      asm volatile("s_waitcnt lgkmcnt(0)" ::: "memory");
      __builtin_amdgcn_sched_barrier(0);
      __builtin_amdgcn_s_setprio(1);
      #pragma unroll
      for (int mf = 0; mf < 8; ++mf)
        #pragma unroll
        for (int nf = 0; nf < 4; ++nf)
          acc[mf][nf] = __builtin_amdgcn_mfma_f32_16x16x32_bf16(
              av[mf], bv[nf], acc[mf][nf], 0, 0, 0);
      __builtin_amdgcn_s_setprio(0);
    }
    cur ^= 1;
  }

  // epilogue
  const int cr = (l >> 4) * 4;
  const int cc = l & 15;
  #pragma unroll
  for (int mf = 0; mf < 8; ++mf) {
    #pragma unroll
    for (int nf = 0; nf < 4; ++nf) {
      int row = m0 + wm * 128 + mf * 16 + cr;
      int col = n0 + wn * 64 + nf * 16 + cc;
      #pragma unroll
      for (int j = 0; j < 4; ++j) {
        float x = acc[mf][nf][j];
        if (EPI == 2) {
          if (col >= 2048) {
            float z = x + bias[col - 2048];
            x = z / (1.f + expf(-z));
          }
        }
        if (EPI == 3)
          ((float*)Cout)[(size_t)(row + j) * N + col] = x;
        else
          ((unsigned short*)Cout)[(size_t)(row + j) * N + col] = f2bf(x);
      }
    }
  }
}

// ----- fused gate path: lg = log_sigmoid((x@Wg1)@Wg2)/16, [M,512] -----
// one block per 16 rows: phase 1 computes t1[16][16] into LDS, phase 2
// each thread emits 32 lg outputs.
__global__ __launch_bounds__(256)
void gemm_g12(const unsigned short* __restrict__ x, const float* __restrict__ W1,
              const float* __restrict__ W2, float* __restrict__ lg)
{
  __shared__ float Xs[16][64];
  __shared__ float Ws[64][16];
  __shared__ float T1[16][16];
  const int tid = threadIdx.x;
  const int m0 = blockIdx.x * 16;
  const int mi = tid >> 4, n = tid & 15;
  float acc = 0.f;
  for (int k0 = 0; k0 < 1024; k0 += 64) {
    ushort4 xv = *(const ushort4*)(x + (size_t)(m0 + (tid >> 4)) * 1024 + k0 + (tid & 15) * 4);
    Xs[tid >> 4][(tid & 15) * 4 + 0] = bf2f(xv.x);
    Xs[tid >> 4][(tid & 15) * 4 + 1] = bf2f(xv.y);
    Xs[tid >> 4][(tid & 15) * 4 + 2] = bf2f(xv.z);
    Xs[tid >> 4][(tid & 15) * 4 + 3] = bf2f(xv.w);
    *(float4*)&Ws[tid >> 2][(tid & 3) * 4] =
        *(const float4*)(W1 + (size_t)(k0 + (tid >> 2)) * 16 + (tid & 3) * 4);
    __syncthreads();
    #pragma unroll
    for (int kk = 0; kk < 64; ++kk)
      acc = fmaf(Xs[mi][kk], Ws[kk][n], acc);
    __syncthreads();
  }
  T1[mi][n] = acc;
  __syncthreads();
  // phase 2: row r = tid>>4, cols (tid&15) + 16*j
  const int r = tid >> 4;
  float t[16];
  #pragma unroll
  for (int kk = 0; kk < 16; ++kk) t[kk] = T1[r][kk];
  #pragma unroll
  for (int j = 0; j < 32; ++j) {
    int col = (tid & 15) + j * 16;
    float a = 0.f;
    #pragma unroll
    for (int kk = 0; kk < 16; ++kk)
      a = fmaf(t[kk], W2[kk * 512 + col], a);
    float ls = fminf(a, 0.f) - log1pf(expf(-fabsf(a)));
    lg[(size_t)(m0 + r) * 512 + col] = ls * 0.0625f;
  }
}

// ============ chunked GLA — MFMA version (fused qkvg input) ============
__global__ __launch_bounds__(256)
void gla_chunk_state(const unsigned short* __restrict__ qkv, const float* __restrict__ lg,
                     float* __restrict__ P, float* __restrict__ Dd)
{
  __shared__ __align__(16) float Lc[CHK][32];
  __shared__ __align__(16) unsigned short kdT[32][72];
  __shared__ __align__(16) unsigned short vT[64][72];
  const int blk = blockIdx.x;
  const int bh = blk >> 6, chunk = blk & (NCHK - 1);
  const int b = bh >> 4, h = bh & 15;
  const int tid = threadIdx.x;
  const int w = tid >> 6, l = tid & 63;
  const size_t rbase = ((size_t)b * Lq + (size_t)chunk * CHK) * QKVS;
  const size_t rowk = rbase + 512 + h * 32;
  const size_t rowv = rbase + 1024 + h * 64;
  const size_t rowl = ((size_t)b * Lq + (size_t)chunk * CHK) * 512 + h * 32;

  #pragma unroll
  for (int r = 0; r < 2; ++r) {
    int s4 = (tid + 256 * r) * 4;
    int t = s4 >> 5, d0 = s4 & 31;
    *(float4*)&Lc[t][d0] = *(const float4*)(lg + rowl + (size_t)t * 512 + d0);
  }
  __syncthreads();
  if (tid < 32) {
    float s = 0.f;
    for (int t = 0; t < CHK; ++t) { s += Lc[t][tid]; Lc[t][tid] = s; }
  }
  __syncthreads();
  #pragma unroll
  for (int r = 0; r < 2; ++r) {
    int s4 = (tid + 256 * r) * 4;
    int t = s4 >> 5, d0 = s4 & 31;
    ushort4 kv = *(const ushort4*)(qkv + rowk + (size_t)t * QKVS + d0);
    float4 lc = *(const float4*)&Lc[t][d0];
    float4 ls = *(const float4*)&Lc[CHK - 1][d0];
    kdT[d0 + 0][t] = f2bf(bf2f(kv.x) * expf(ls.x - lc.x));
    kdT[d0 + 1][t] = f2bf(bf2f(kv.y) * expf(ls.y - lc.y));
    kdT[d0 + 2][t] = f2bf(bf2f(kv.z) * expf(ls.z - lc.z));
    kdT[d0 + 3][t] = f2bf(bf2f(kv.w) * expf(ls.w - lc.w));
  }
  #pragma unroll
  for (int r = 0; r < 4; ++r) {
    int s4 = (tid + 256 * r) * 4;
    int t = s4 >> 6, e0 = s4 & 63;
    ushort4 vv = *(const ushort4*)(qkv + rowv + (size_t)t * QKVS + e0);
    vT[e0 + 0][t] = vv.x;
    vT[e0 + 1][t] = vv.y;
    vT[e0 + 2][t] = vv.z;
    vT[e0 + 3][t] = vv.w;
  }
  __syncthreads();
  #pragma unroll
  for (int dj = 0; dj < 2; ++dj) {
    f32x4 acc = (f32x4){0.f, 0.f, 0.f, 0.f};
    #pragma unroll
    for (int ks = 0; ks < 2; ++ks) {
      short8 aV = *(const short8*)((const char*)&vT[0][0] +
                    (16 * w + (l & 15)) * 144 + ks * 64 + (l >> 4) * 16);
      short8 bK = *(const short8*)((const char*)&kdT[0][0] +
                    (16 * dj + (l & 15)) * 144 + ks * 64 + (l >> 4) * 16);
      acc = __builtin_amdgcn_mfma_f32_16x16x32_bf16(aV, bK, acc, 0, 0, 0);
    }
    #pragma unroll
    for (int j = 0; j < 4; ++j) {
      int e = 16 * w + (l >> 4) * 4 + j;
      int d = 16 * dj + (l & 15);
      P[(size_t)blk * 2048 + e * 32 + d] = acc[j];
    }
  }
  if (tid < 32) Dd[(size_t)blk * 32 + tid] = expf(Lc[CHK - 1][tid]);
}

__global__ __launch_bounds__(256)
void gla_chain(float* __restrict__ P, const float* __restrict__ Dd)
{
  const int bh = blockIdx.x;
  const int tid = threadIdx.x;
  float4 sA = {0.f, 0.f, 0.f, 0.f}, sB = {0.f, 0.f, 0.f, 0.f};
  const int fA = tid * 4, fB = tid * 4 + 1024;
  const int d0 = fA & 31;
  for (int i = 0; i < NCHK; ++i) {
    const size_t base = ((size_t)bh * NCHK + i) * 2048;
    float4 dd = *(const float4*)(Dd + ((size_t)bh * NCHK + i) * 32 + d0);
    float4 pa = *(const float4*)(P + base + fA);
    float4 pb = *(const float4*)(P + base + fB);
    *(float4*)(P + base + fA) = sA;
    *(float4*)(P + base + fB) = sB;
    sA.x = fmaf(sA.x, dd.x, pa.x); sA.y = fmaf(sA.y, dd.y, pa.y);
    sA.z = fmaf(sA.z, dd.z, pa.z); sA.w = fmaf(sA.w, dd.w, pa.w);
    sB.x = fmaf(sB.x, dd.x, pb.x); sB.y = fmaf(sB.y, dd.y, pb.y);
    sB.z = fmaf(sB.z, dd.z, pb.z); sB.w = fmaf(sB.w, dd.w, pb.w);
  }
}

// chunk_out + fused group-norm + gate multiply -> bf16 gated [M][1024]
__global__ __launch_bounds__(256)
void gla_chunk_out(const unsigned short* __restrict__ qkv, const float* __restrict__ lg,
                   const float* __restrict__ S, unsigned short* __restrict__ gated)
{
  __shared__ __align__(16) float Lc[CHK][32];
  __shared__ __align__(16) unsigned short qb[CHK][40];
  __shared__ __align__(16) unsigned short kd[CHK][40];
  __shared__ __align__(16) unsigned short vT[64][72];
  __shared__ __align__(16) unsigned short ST[64][40];
  __shared__ __align__(16) unsigned short Aq[64][72];
  const int blk = blockIdx.x;
  const int bh = blk >> 6, chunk = blk & (NCHK - 1);
  const int b = bh >> 4, h = bh & 15;
  const int tid = threadIdx.x;
  const int w = tid >> 6, l = tid & 63;
  const size_t rbase = ((size_t)b * Lq + (size_t)chunk * CHK) * QKVS;
  const size_t rowq = rbase + h * 32;
  const size_t rowk = rbase + 512 + h * 32;
  const size_t rowv = rbase + 1024 + h * 64;
  const size_t rowl = ((size_t)b * Lq + (size_t)chunk * CHK) * 512 + h * 32;

  #pragma unroll
  for (int r = 0; r < 2; ++r) {
    int s4 = (tid + 256 * r) * 4;
    int t = s4 >> 5, d0 = s4 & 31;
    *(float4*)&Lc[t][d0] = *(const float4*)(lg + rowl + (size_t)t * 512 + d0);
  }
  __syncthreads();
  if (tid < 32) {
    float s = 0.f;
    for (int t = 0; t < CHK; ++t) { s += Lc[t][tid]; Lc[t][tid] = s; }
  }
  __syncthreads();
  #pragma unroll
  for (int r = 0; r < 2; ++r) {
    int s4 = (tid + 256 * r) * 4;
    int t = s4 >> 5, d0 = s4 & 31;
    ushort4 kv = *(const ushort4*)(qkv + rowk + (size_t)t * QKVS + d0);
    ushort4 qv = *(const ushort4*)(qkv + rowq + (size_t)t * QKVS + d0);
    float4 lc = *(const float4*)&Lc[t][d0];
    ushort4 ko, qo;
    ko.x = f2bf(bf2f(kv.x) * expf(-lc.x)); qo.x = f2bf(bf2f(qv.x) * expf(lc.x));
    ko.y = f2bf(bf2f(kv.y) * expf(-lc.y)); qo.y = f2bf(bf2f(qv.y) * expf(lc.y));
    ko.z = f2bf(bf2f(kv.z) * expf(-lc.z)); qo.z = f2bf(bf2f(qv.z) * expf(lc.z));
    ko.w = f2bf(bf2f(kv.w) * expf(-lc.w)); qo.w = f2bf(bf2f(qv.w) * expf(lc.w));
    *(ushort4*)&kd[t][d0] = ko;
    *(ushort4*)&qb[t][d0] = qo;
  }
  #pragma unroll
  for (int r = 0; r < 4; ++r) {
    int s4 = (tid + 256 * r) * 4;
    int t = s4 >> 6, e0 = s4 & 63;
    ushort4 vv = *(const ushort4*)(qkv + rowv + (size_t)t * QKVS + e0);
    vT[e0 + 0][t] = vv.x;
    vT[e0 + 1][t] = vv.y;
    vT[e0 + 2][t] = vv.z;
    vT[e0 + 3][t] = vv.w;
  }
  #pragma unroll
  for (int r = 0; r < 2; ++r) {
    int s4 = (tid + 256 * r) * 4;
    int e = s4 >> 5, d0 = s4 & 31;
    float4 f = *(const float4*)(S + (size_t)blk * 2048 + s4);
    ushort4 u = make_ushort4(f2bf(f.x), f2bf(f.y), f2bf(f.z), f2bf(f.w));
    *(ushort4*)&ST[e][d0] = u;
  }
  __syncthreads();

  short8 aQ = *(const short8*)((const char*)&qb[0][0] +
               (16 * w + (l & 15)) * 80 + (l >> 4) * 16);
  const int tl0 = (l >> 4) * 4;
  #pragma unroll
  for (int si = 0; si < 4; ++si) {
    if (si <= w) {
      short8 bK = *(const short8*)((const char*)&kd[0][0] +
                   (16 * si + (l & 15)) * 80 + (l >> 4) * 16);
      f32x4 acc = (f32x4){0.f, 0.f, 0.f, 0.f};
      acc = __builtin_amdgcn_mfma_f32_16x16x32_bf16(aQ, bK, acc, 0, 0, 0);
      #pragma unroll
      for (int j = 0; j < 4; ++j) {
        bool keep = (si < w) || ((l & 15) <= tl0 + j);
        Aq[16 * w + tl0 + j][16 * si + (l & 15)] = keep ? f2bf(acc[j]) : 0;
      }
    } else {
      #pragma unroll
      for (int j = 0; j < 4; ++j)
        Aq[16 * w + tl0 + j][16 * si + (l & 15)] = 0;
    }
  }
  __syncthreads();

  short8 aA0 = *(const short8*)((const char*)&Aq[0][0] +
                (16 * w + (l & 15)) * 144 + (l >> 4) * 16);
  short8 aA1 = *(const short8*)((const char*)&Aq[0][0] +
                (16 * w + (l & 15)) * 144 + 64 + (l >> 4) * 16);
  f32x4 accs[4];
  #pragma unroll
  for (int ej = 0; ej < 4; ++ej) {
    f32x4 acc = (f32x4){0.f, 0.f, 0.f, 0.f};
    short8 bV0 = *(const short8*)((const char*)&vT[0][0] +
                  (16 * ej + (l & 15)) * 144 + (l >> 4) * 16);
    short8 bV1 = *(const short8*)((const char*)&vT[0][0] +
                  (16 * ej + (l & 15)) * 144 + 64 + (l >> 4) * 16);
    short8 bS = *(const short8*)((const char*)&ST[0][0] +
                  (16 * ej + (l & 15)) * 80 + (l >> 4) * 16);
    acc = __builtin_amdgcn_mfma_f32_16x16x32_bf16(aA0, bV0, acc, 0, 0, 0);
    acc = __builtin_amdgcn_mfma_f32_16x16x32_bf16(aA1, bV1, acc, 0, 0, 0);
    acc = __builtin_amdgcn_mfma_f32_16x16x32_bf16(aQ,  bS,  acc, 0, 0, 0);
    accs[ej] = acc;
  }

  float mean[4], rstd[4];
  #pragma unroll
  for (int j = 0; j < 4; ++j) {
    float s  = accs[0][j] + accs[1][j] + accs[2][j] + accs[3][j];
    float q2 = accs[0][j] * accs[0][j] + accs[1][j] * accs[1][j]
             + accs[2][j] * accs[2][j] + accs[3][j] * accs[3][j];
    #pragma unroll
    for (int m = 1; m <= 8; m <<= 1) {
      s  += __shfl_xor(s, m, 64);
      q2 += __shfl_xor(q2, m, 64);
    }
    float mu = s * (1.f / 64.f);
    mean[j] = mu;
    rstd[j] = rsqrtf(q2 * (1.f / 64.f) - mu * mu + kEps);
  }

  const size_t gbase = rbase + 2048 + h * 64;
  const size_t obase = ((size_t)b * Lq + (size_t)chunk * CHK) * 1024 + h * 64;
  #pragma unroll
  for (int ej = 0; ej < 4; ++ej) {
    int e = 16 * ej + (l & 15);
    #pragma unroll
    for (int j = 0; j < 4; ++j) {
      int t = 16 * w + tl0 + j;
      float gate = bf2f(qkv[gbase + (size_t)t * QKVS + e]);
      float y = (accs[ej][j] - mean[j]) * rstd[j];
      gated[obase + (size_t)t * 1024 + e] = f2bf(gate * y);
    }
  }
}

} // namespace

extern "C" void kernel_launch(void* const* d_in, const int* in_sizes, int n_in,
                              void* d_out, int out_size, void* d_ws, size_t ws_size,
                              hipStream_t stream)
{
  (void)in_sizes; (void)n_in; (void)out_size; (void)ws_size;
  const float* x   = (const float*)d_in[0];
  const float* Wq  = (const float*)d_in[1];
  const float* Wk  = (const float*)d_in[2];
  const float* Wg1 = (const float*)d_in[3];
  const float* Wg2 = (const float*)d_in[4];
  const float* Wv  = (const float*)d_in[5];
  const float* Wg  = (const float*)d_in[6];
  const float* bg  = (const float*)d_in[7];
  const float* Wo  = (const float*)d_in[8];

  // workspace: 211.3 MB total
  char* w = (char*)d_ws;
  unsigned short* xh   = (unsigned short*)w; w += (size_t)Mrows * 1024 * 2;
  unsigned short* qkvg = (unsigned short*)w; w += (size_t)Mrows * QKVS * 2;
  float*  lgb = (float*)w;                   w += (size_t)Mrows * 512 * 4;
  float*  t1  = (float*)w;                   w += (size_t)Mrows * 16 * 4;  (void)t1;
  float*  Pst = (float*)w;                   w += (size_t)64 * NCHK * 2048 * 4;
  float*  Dd  = (float*)w;                   w += (size_t)64 * NCHK * 32 * 4;
  unsigned short* Wqkvgt = (unsigned short*)w; w += (size_t)QKVS * 1024 * 2;
  unsigned short* Wot    = (unsigned short*)w; w += (size_t)1024 * 1024 * 2;
  unsigned short* gated  = xh;   // alias: xh dead after proj GEMM + gemm_g12

  cvt_bf16<<<2048, 256, 0, stream>>>(x, xh, Mrows * 1024 / 4);
  cvt_w_t<<<dim3(8, 16),  256, 0, stream>>>(Wq, Wqkvgt, 1024, 512, 1.f);
  cvt_w_t<<<dim3(8, 16),  256, 0, stream>>>(Wk, Wqkvgt + (size_t)512 * 1024, 1024, 512, kScale);
  cvt_w_t<<<dim3(16, 16), 256, 0, stream>>>(Wv, Wqkvgt + (size_t)1024 * 1024, 1024, 1024, 1.f);
  cvt_w_t<<<dim3(16, 16), 256, 0, stream>>>(Wg, Wqkvgt + (size_t)2048 * 1024, 1024, 1024, 1.f);
  cvt_w_t<<<dim3(16, 16), 256, 0, stream>>>(Wo, Wot, 1024, 1024, 1.f);
  // fused q|k|v|gate projection (R11-verified 256^2 MFMA)
  gemm256<2><<<dim3(12, 64), 512, 0, stream>>>(xh, Wqkvgt, bg, qkvg, QKVS);
  // fused gate-logit path (g1+g2 in one kernel)
  gemm_g12<<<Mrows / 16, 256, 0, stream>>>(xh, Wg1, Wg2, lgb);
  // chunked recurrence (MFMA) + fused gnorm/gate epilogue
  gla_chunk_state<<<64 * NCHK, 256, 0, stream>>>(qkvg, lgb, Pst, Dd);
  gla_chain<<<64, 256, 0, stream>>>(Pst, Dd);
  gla_chunk_out<<<64 * NCHK, 256, 0, stream>>>(qkvg, lgb, Pst, gated);
  // output projection (fp32 out)
  gemm256<3><<<dim3(4, 64), 512, 0, stream>>>(gated, Wot, nullptr, d_out, 1024);
}

// Round 15
// 359.072 us; speedup vs baseline: 1.2224x; 1.2224x over previous
//
#include <hip/hip_runtime.h>
#include <cstdint>

namespace {

constexpr int Lq  = 4096;
constexpr int Bq  = 4;
constexpr int H_  = 16;
constexpr int Mrows = Bq * Lq;               // 16384
constexpr int CHK  = 64;
constexpr int NCHK = Lq / CHK;               // 64
constexpr int QKVS = 3072;                   // fused q|k|v|gate row stride
constexpr float kScale = 0.17677669529663687f;  // 32^-0.5
constexpr float kEps   = 1e-5f;

typedef __attribute__((ext_vector_type(8))) short short8;
typedef __attribute__((ext_vector_type(4))) float f32x4;

__device__ __forceinline__ float bf2f(unsigned short u) {
  return __uint_as_float(((unsigned)u) << 16);
}
__device__ __forceinline__ unsigned short f2bf(float f) {
  unsigned u = __float_as_uint(f);
  u += 0x7fffu + ((u >> 16) & 1u);   // RNE
  return (unsigned short)(u >> 16);
}
__device__ __forceinline__ void gload_lds16(const void* g, void* l) {
  __builtin_amdgcn_global_load_lds(
      (const __attribute__((address_space(1))) void*)g,
      (__attribute__((address_space(3))) void*)l, 16, 0, 0);
}

// ---------- x fp32 -> bf16 ----------
__global__ __launch_bounds__(256)
void cvt_bf16(const float* __restrict__ in, unsigned short* __restrict__ out, int n4)
{
  int i = blockIdx.x * 256 + threadIdx.x;
  const int stride = gridDim.x * 256;
  for (; i < n4; i += stride) {
    float4 f = ((const float4*)in)[i];
    ushort4 u = make_ushort4(f2bf(f.x), f2bf(f.y), f2bf(f.z), f2bf(f.w));
    ((ushort4*)out)[i] = u;
  }
}

// ---------- batched W[K,N] fp32 -> Wt[N,K] bf16 (5 weights, 1 dispatch) ----------
struct CvtArgs {
  const float* W[5];
  unsigned short* Wt[5];
  int   N[5];       // source cols
  float scale[5];
  int   start[5];   // first flat block of segment
  int   nb[5];      // n-blocks (N/64) per segment
};

__global__ __launch_bounds__(256)
void cvt_w_all(CvtArgs a)
{
  __shared__ float T[64][65];
  const int tid = threadIdx.x;
  const int b = blockIdx.x;
  int seg = 0;
  #pragma unroll
  for (int i = 1; i < 5; ++i) seg += (b >= a.start[i]) ? 1 : 0;
  const float* W = a.W[seg];
  unsigned short* Wt = a.Wt[seg];
  const int N = a.N[seg];
  const float scale = a.scale[seg];
  const int lb = b - a.start[seg];
  const int n0 = (lb % a.nb[seg]) * 64;
  const int k0 = (lb / a.nb[seg]) * 64;

  #pragma unroll
  for (int it = 0; it < 4; ++it) {
    int kr = (tid >> 4) + it * 16;
    float4 f = *(const float4*)(W + (size_t)(k0 + kr) * N + n0 + (tid & 15) * 4);
    T[kr][(tid & 15) * 4 + 0] = f.x;
    T[kr][(tid & 15) * 4 + 1] = f.y;
    T[kr][(tid & 15) * 4 + 2] = f.z;
    T[kr][(tid & 15) * 4 + 3] = f.w;
  }
  __syncthreads();
  #pragma unroll
  for (int it = 0; it < 4; ++it) {
    int nr = (tid >> 4) + it * 16;
    int c0 = (tid & 15) * 4;
    ushort4 u = make_ushort4(f2bf(T[c0 + 0][nr] * scale), f2bf(T[c0 + 1][nr] * scale),
                             f2bf(T[c0 + 2][nr] * scale), f2bf(T[c0 + 3][nr] * scale));
    *(ushort4*)(Wt + (size_t)(n0 + nr) * 1024 + k0 + c0) = u;
  }
}

// ========== 256x256 8-wave bf16 GEMM, K=1024, 1 barrier/K-tile ==========
// (R11 verified best: 157 us @ N=3072.) Per K-tile: {vmcnt(0); barrier;
// issue 8 next-tile loads} then 2 K-half phases of {12 ds_read (each
// fragment ONCE) -> lgkmcnt(0) -> 32 MFMA}. No intra-tile barriers.
// EPI: 2 = silu(x+bias[col-2048]) for col>=2048, store bf16
//      3 = plain, store fp32
template<int EPI>
__global__ __launch_bounds__(512, 1)
void gemm256(const unsigned short* __restrict__ A,
             const unsigned short* __restrict__ Bt,
             const float* __restrict__ bias,
             void* __restrict__ Cout, int N)
{
  __shared__ __align__(16) unsigned short As[2][256 * 64];
  __shared__ __align__(16) unsigned short Bs[2][256 * 64];
  const int tid = threadIdx.x;
  const int w = tid >> 6, l = tid & 63;
  const int wm = w >> 2, wn = w & 3;

  const int nbx = gridDim.x;
  const int bid = blockIdx.y * nbx + blockIdx.x;
  const int xcd = bid & 7;
  const int idx = bid >> 3;
  const int nsup = idx >> 4;           // 16 = 8 mPanels * 2 ni
  const int rem = idx & 15;
  const int mi = rem >> 1, ni = rem & 1;
  const int m0 = (xcd * 8 + mi) * 256;
  const int n0 = (nsup * 2 + ni) * 256;

  const int srow = tid >> 3;
  const int scol = ((tid & 7) ^ ((tid >> 3) & 7)) * 8;
  const unsigned short* gAp[4];
  const unsigned short* gBp[4];
  #pragma unroll
  for (int i = 0; i < 4; ++i) {
    gAp[i] = A  + (size_t)(m0 + i * 64 + srow) * 1024 + scol;
    gBp[i] = Bt + (size_t)(n0 + i * 64 + srow) * 1024 + scol;
  }

  const int rbA = wm * 128 + (l & 15);
  const int rbB = wn * 64 + (l & 15);
  const int swzA = (rbA & 7) << 4;
  const int swzB = (rbB & 7) << 4;
  const int colb = (l >> 4) * 16;

  f32x4 acc[8][4];
  #pragma unroll
  for (int i = 0; i < 8; ++i)
    #pragma unroll
    for (int j = 0; j < 4; ++j)
      acc[i][j] = (f32x4){0.f, 0.f, 0.f, 0.f};

  // prologue: stage tile 0 into buf 0
  #pragma unroll
  for (int i = 0; i < 4; ++i) {
    gload_lds16(gAp[i], (char*)&As[0][0] + i * 8192 + w * 1024);
    gload_lds16(gBp[i], (char*)&Bs[0][0] + i * 8192 + w * 1024);
    gAp[i] += 64; gBp[i] += 64;
  }

  int cur = 0;
  for (int t = 0; t < 16; ++t) {
    char* ldsA  = (char*)&As[cur][0];
    char* ldsB  = (char*)&Bs[cur][0];
    char* ldsAn = (char*)&As[cur ^ 1][0];
    char* ldsBn = (char*)&Bs[cur ^ 1][0];

    asm volatile("s_waitcnt vmcnt(0)" ::: "memory");
    __builtin_amdgcn_s_barrier();
    __builtin_amdgcn_sched_barrier(0);
    if (t < 15) {
      #pragma unroll
      for (int i = 0; i < 4; ++i) {
        gload_lds16(gAp[i], ldsAn + i * 8192 + w * 1024);
        gload_lds16(gBp[i], ldsBn + i * 8192 + w * 1024);
        gAp[i] += 64; gBp[i] += 64;
      }
    }

    #pragma unroll
    for (int ks = 0; ks < 2; ++ks) {
      short8 av[8], bv[4];
      #pragma unroll
      for (int mf = 0; mf < 8; ++mf) {
        int row = rbA + mf * 16;
        av[mf] = *(const short8*)(ldsA + row * 128 + ((ks * 64 + colb) ^ swzA));
      }
      #pragma unroll
      for (int nf = 0; nf < 4; ++nf) {
        int row = rbB + nf * 16;
        bv[nf] = *(const short8*)(ldsB + row * 128 + ((ks * 64 + colb) ^ swzB));
      }
      asm volatile("s_waitcnt lgkmcnt(0)" ::: "memory");
      __builtin_amdgcn_sched_barrier(0);
      __builtin_amdgcn_s_setprio(1);
      #pragma unroll
      for (int mf = 0; mf < 8; ++mf)
        #pragma unroll
        for (int nf = 0; nf < 4; ++nf)
          acc[mf][nf] = __builtin_amdgcn_mfma_f32_16x16x32_bf16(
              av[mf], bv[nf], acc[mf][nf], 0, 0, 0);
      __builtin_amdgcn_s_setprio(0);
    }
    cur ^= 1;
  }

  // epilogue
  const int cr = (l >> 4) * 4;
  const int cc = l & 15;
  #pragma unroll
  for (int mf = 0; mf < 8; ++mf) {
    #pragma unroll
    for (int nf = 0; nf < 4; ++nf) {
      int row = m0 + wm * 128 + mf * 16 + cr;
      int col = n0 + wn * 64 + nf * 16 + cc;
      #pragma unroll
      for (int j = 0; j < 4; ++j) {
        float x = acc[mf][nf][j];
        if (EPI == 2) {
          if (col >= 2048) {
            float z = x + bias[col - 2048];
            x = z / (1.f + expf(-z));
          }
        }
        if (EPI == 3)
          ((float*)Cout)[(size_t)(row + j) * N + col] = x;
        else
          ((unsigned short*)Cout)[(size_t)(row + j) * N + col] = f2bf(x);
      }
    }
  }
}

// ---------------- t1 = x_bf16[M,1024] @ Wg1[1024,16] (fp32 acc) ----------------
__global__ __launch_bounds__(256)
void gemm_g1(const unsigned short* __restrict__ x, const float* __restrict__ W1,
             float* __restrict__ t1)
{
  __shared__ float Xs[16][64];
  __shared__ float Ws[64][16];
  const int tid = threadIdx.x;
  const int m0 = blockIdx.x * 16;
  const int mi = tid >> 4, n = tid & 15;
  float acc = 0.f;
  for (int k0 = 0; k0 < 1024; k0 += 64) {
    ushort4 xv = *(const ushort4*)(x + (size_t)(m0 + (tid >> 4)) * 1024 + k0 + (tid & 15) * 4);
    Xs[tid >> 4][(tid & 15) * 4 + 0] = bf2f(xv.x);
    Xs[tid >> 4][(tid & 15) * 4 + 1] = bf2f(xv.y);
    Xs[tid >> 4][(tid & 15) * 4 + 2] = bf2f(xv.z);
    Xs[tid >> 4][(tid & 15) * 4 + 3] = bf2f(xv.w);
    *(float4*)&Ws[tid >> 2][(tid & 3) * 4] =
        *(const float4*)(W1 + (size_t)(k0 + (tid >> 2)) * 16 + (tid & 3) * 4);
    __syncthreads();
    #pragma unroll
    for (int kk = 0; kk < 64; ++kk)
      acc = fmaf(Xs[mi][kk], Ws[kk][n], acc);
    __syncthreads();
  }
  t1[(size_t)(m0 + mi) * 16 + n] = acc;
}

// --------- lg = log_sigmoid(t1 @ Wg2) / 16,  [M, 512] fp32 ---------
__global__ __launch_bounds__(256)
void gemm_g2(const float* __restrict__ t1, const float* __restrict__ W2,
             float* __restrict__ lg)
{
  const int idx = blockIdx.x * 256 + threadIdx.x;
  const int m = idx >> 9, n = idx & 511;
  float acc = 0.f;
  #pragma unroll
  for (int kk = 0; kk < 16; ++kk)
    acc = fmaf(t1[m * 16 + kk], W2[kk * 512 + n], acc);
  float ls = fminf(acc, 0.f) - log1pf(expf(-fabsf(acc)));
  lg[idx] = ls * 0.0625f;
}

// ============ chunked GLA — MFMA version (fused qkvg input) ============
__global__ __launch_bounds__(256)
void gla_chunk_state(const unsigned short* __restrict__ qkv, const float* __restrict__ lg,
                     float* __restrict__ P, float* __restrict__ Dd)
{
  __shared__ __align__(16) float Lc[CHK][32];
  __shared__ __align__(16) unsigned short kdT[32][72];
  __shared__ __align__(16) unsigned short vT[64][72];
  const int blk = blockIdx.x;
  const int bh = blk >> 6, chunk = blk & (NCHK - 1);
  const int b = bh >> 4, h = bh & 15;
  const int tid = threadIdx.x;
  const int w = tid >> 6, l = tid & 63;
  const size_t rbase = ((size_t)b * Lq + (size_t)chunk * CHK) * QKVS;
  const size_t rowk = rbase + 512 + h * 32;
  const size_t rowv = rbase + 1024 + h * 64;
  const size_t rowl = ((size_t)b * Lq + (size_t)chunk * CHK) * 512 + h * 32;

  #pragma unroll
  for (int r = 0; r < 2; ++r) {
    int s4 = (tid + 256 * r) * 4;
    int t = s4 >> 5, d0 = s4 & 31;
    *(float4*)&Lc[t][d0] = *(const float4*)(lg + rowl + (size_t)t * 512 + d0);
  }
  __syncthreads();
  if (tid < 32) {
    float s = 0.f;
    for (int t = 0; t < CHK; ++t) { s += Lc[t][tid]; Lc[t][tid] = s; }
  }
  __syncthreads();
  #pragma unroll
  for (int r = 0; r < 2; ++r) {
    int s4 = (tid + 256 * r) * 4;
    int t = s4 >> 5, d0 = s4 & 31;
    ushort4 kv = *(const ushort4*)(qkv + rowk + (size_t)t * QKVS + d0);
    float4 lc = *(const float4*)&Lc[t][d0];
    float4 ls = *(const float4*)&Lc[CHK - 1][d0];
    kdT[d0 + 0][t] = f2bf(bf2f(kv.x) * expf(ls.x - lc.x));
    kdT[d0 + 1][t] = f2bf(bf2f(kv.y) * expf(ls.y - lc.y));
    kdT[d0 + 2][t] = f2bf(bf2f(kv.z) * expf(ls.z - lc.z));
    kdT[d0 + 3][t] = f2bf(bf2f(kv.w) * expf(ls.w - lc.w));
  }
  #pragma unroll
  for (int r = 0; r < 4; ++r) {
    int s4 = (tid + 256 * r) * 4;
    int t = s4 >> 6, e0 = s4 & 63;
    ushort4 vv = *(const ushort4*)(qkv + rowv + (size_t)t * QKVS + e0);
    vT[e0 + 0][t] = vv.x;
    vT[e0 + 1][t] = vv.y;
    vT[e0 + 2][t] = vv.z;
    vT[e0 + 3][t] = vv.w;
  }
  __syncthreads();
  #pragma unroll
  for (int dj = 0; dj < 2; ++dj) {
    f32x4 acc = (f32x4){0.f, 0.f, 0.f, 0.f};
    #pragma unroll
    for (int ks = 0; ks < 2; ++ks) {
      short8 aV = *(const short8*)((const char*)&vT[0][0] +
                    (16 * w + (l & 15)) * 144 + ks * 64 + (l >> 4) * 16);
      short8 bK = *(const short8*)((const char*)&kdT[0][0] +
                    (16 * dj + (l & 15)) * 144 + ks * 64 + (l >> 4) * 16);
      acc = __builtin_amdgcn_mfma_f32_16x16x32_bf16(aV, bK, acc, 0, 0, 0);
    }
    #pragma unroll
    for (int j = 0; j < 4; ++j) {
      int e = 16 * w + (l >> 4) * 4 + j;
      int d = 16 * dj + (l & 15);
      P[(size_t)blk * 2048 + e * 32 + d] = acc[j];
    }
  }
  if (tid < 32) Dd[(size_t)blk * 32 + tid] = expf(Lc[CHK - 1][tid]);
}

__global__ __launch_bounds__(256)
void gla_chain(float* __restrict__ P, const float* __restrict__ Dd)
{
  const int bh = blockIdx.x;
  const int tid = threadIdx.x;
  float4 sA = {0.f, 0.f, 0.f, 0.f}, sB = {0.f, 0.f, 0.f, 0.f};
  const int fA = tid * 4, fB = tid * 4 + 1024;
  const int d0 = fA & 31;
  for (int i = 0; i < NCHK; ++i) {
    const size_t base = ((size_t)bh * NCHK + i) * 2048;
    float4 dd = *(const float4*)(Dd + ((size_t)bh * NCHK + i) * 32 + d0);
    float4 pa = *(const float4*)(P + base + fA);
    float4 pb = *(const float4*)(P + base + fB);
    *(float4*)(P + base + fA) = sA;
    *(float4*)(P + base + fB) = sB;
    sA.x = fmaf(sA.x, dd.x, pa.x); sA.y = fmaf(sA.y, dd.y, pa.y);
    sA.z = fmaf(sA.z, dd.z, pa.z); sA.w = fmaf(sA.w, dd.w, pa.w);
    sB.x = fmaf(sB.x, dd.x, pb.x); sB.y = fmaf(sB.y, dd.y, pb.y);
    sB.z = fmaf(sB.z, dd.z, pb.z); sB.w = fmaf(sB.w, dd.w, pb.w);
  }
}

// chunk_out + fused group-norm + gate multiply -> bf16 gated [M][1024]
__global__ __launch_bounds__(256)
void gla_chunk_out(const unsigned short* __restrict__ qkv, const float* __restrict__ lg,
                   const float* __restrict__ S, unsigned short* __restrict__ gated)
{
  __shared__ __align__(16) float Lc[CHK][32];
  __shared__ __align__(16) unsigned short qb[CHK][40];
  __shared__ __align__(16) unsigned short kd[CHK][40];
  __shared__ __align__(16) unsigned short vT[64][72];
  __shared__ __align__(16) unsigned short ST[64][40];
  __shared__ __align__(16) unsigned short Aq[64][72];
  const int blk = blockIdx.x;
  const int bh = blk >> 6, chunk = blk & (NCHK - 1);
  const int b = bh >> 4, h = bh & 15;
  const int tid = threadIdx.x;
  const int w = tid >> 6, l = tid & 63;
  const size_t rbase = ((size_t)b * Lq + (size_t)chunk * CHK) * QKVS;
  const size_t rowq = rbase + h * 32;
  const size_t rowk = rbase + 512 + h * 32;
  const size_t rowv = rbase + 1024 + h * 64;
  const size_t rowl = ((size_t)b * Lq + (size_t)chunk * CHK) * 512 + h * 32;

  #pragma unroll
  for (int r = 0; r < 2; ++r) {
    int s4 = (tid + 256 * r) * 4;
    int t = s4 >> 5, d0 = s4 & 31;
    *(float4*)&Lc[t][d0] = *(const float4*)(lg + rowl + (size_t)t * 512 + d0);
  }
  __syncthreads();
  if (tid < 32) {
    float s = 0.f;
    for (int t = 0; t < CHK; ++t) { s += Lc[t][tid]; Lc[t][tid] = s; }
  }
  __syncthreads();
  #pragma unroll
  for (int r = 0; r < 2; ++r) {
    int s4 = (tid + 256 * r) * 4;
    int t = s4 >> 5, d0 = s4 & 31;
    ushort4 kv = *(const ushort4*)(qkv + rowk + (size_t)t * QKVS + d0);
    ushort4 qv = *(const ushort4*)(qkv + rowq + (size_t)t * QKVS + d0);
    float4 lc = *(const float4*)&Lc[t][d0];
    ushort4 ko, qo;
    ko.x = f2bf(bf2f(kv.x) * expf(-lc.x)); qo.x = f2bf(bf2f(qv.x) * expf(lc.x));
    ko.y = f2bf(bf2f(kv.y) * expf(-lc.y)); qo.y = f2bf(bf2f(qv.y) * expf(lc.y));
    ko.z = f2bf(bf2f(kv.z) * expf(-lc.z)); qo.z = f2bf(bf2f(qv.z) * expf(lc.z));
    ko.w = f2bf(bf2f(kv.w) * expf(-lc.w)); qo.w = f2bf(bf2f(qv.w) * expf(lc.w));
    *(ushort4*)&kd[t][d0] = ko;
    *(ushort4*)&qb[t][d0] = qo;
  }
  #pragma unroll
  for (int r = 0; r < 4; ++r) {
    int s4 = (tid + 256 * r) * 4;
    int t = s4 >> 6, e0 = s4 & 63;
    ushort4 vv = *(const ushort4*)(qkv + rowv + (size_t)t * QKVS + e0);
    vT[e0 + 0][t] = vv.x;
    vT[e0 + 1][t] = vv.y;
    vT[e0 + 2][t] = vv.z;
    vT[e0 + 3][t] = vv.w;
  }
  #pragma unroll
  for (int r = 0; r < 2; ++r) {
    int s4 = (tid + 256 * r) * 4;
    int e = s4 >> 5, d0 = s4 & 31;
    float4 f = *(const float4*)(S + (size_t)blk * 2048 + s4);
    ushort4 u = make_ushort4(f2bf(f.x), f2bf(f.y), f2bf(f.z), f2bf(f.w));
    *(ushort4*)&ST[e][d0] = u;
  }
  __syncthreads();

  short8 aQ = *(const short8*)((const char*)&qb[0][0] +
               (16 * w + (l & 15)) * 80 + (l >> 4) * 16);
  const int tl0 = (l >> 4) * 4;
  #pragma unroll
  for (int si = 0; si < 4; ++si) {
    if (si <= w) {
      short8 bK = *(const short8*)((const char*)&kd[0][0] +
                   (16 * si + (l & 15)) * 80 + (l >> 4) * 16);
      f32x4 acc = (f32x4){0.f, 0.f, 0.f, 0.f};
      acc = __builtin_amdgcn_mfma_f32_16x16x32_bf16(aQ, bK, acc, 0, 0, 0);
      #pragma unroll
      for (int j = 0; j < 4; ++j) {
        bool keep = (si < w) || ((l & 15) <= tl0 + j);
        Aq[16 * w + tl0 + j][16 * si + (l & 15)] = keep ? f2bf(acc[j]) : 0;
      }
    } else {
      #pragma unroll
      for (int j = 0; j < 4; ++j)
        Aq[16 * w + tl0 + j][16 * si + (l & 15)] = 0;
    }
  }
  __syncthreads();

  short8 aA0 = *(const short8*)((const char*)&Aq[0][0] +
                (16 * w + (l & 15)) * 144 + (l >> 4) * 16);
  short8 aA1 = *(const short8*)((const char*)&Aq[0][0] +
                (16 * w + (l & 15)) * 144 + 64 + (l >> 4) * 16);
  f32x4 accs[4];
  #pragma unroll
  for (int ej = 0; ej < 4; ++ej) {
    f32x4 acc = (f32x4){0.f, 0.f, 0.f, 0.f};
    short8 bV0 = *(const short8*)((const char*)&vT[0][0] +
                  (16 * ej + (l & 15)) * 144 + (l >> 4) * 16);
    short8 bV1 = *(const short8*)((const char*)&vT[0][0] +
                  (16 * ej + (l & 15)) * 144 + 64 + (l >> 4) * 16);
    short8 bS = *(const short8*)((const char*)&ST[0][0] +
                  (16 * ej + (l & 15)) * 80 + (l >> 4) * 16);
    acc = __builtin_amdgcn_mfma_f32_16x16x32_bf16(aA0, bV0, acc, 0, 0, 0);
    acc = __builtin_amdgcn_mfma_f32_16x16x32_bf16(aA1, bV1, acc, 0, 0, 0);
    acc = __builtin_amdgcn_mfma_f32_16x16x32_bf16(aQ,  bS,  acc, 0, 0, 0);
    accs[ej] = acc;
  }

  float mean[4], rstd[4];
  #pragma unroll
  for (int j = 0; j < 4; ++j) {
    float s  = accs[0][j] + accs[1][j] + accs[2][j] + accs[3][j];
    float q2 = accs[0][j] * accs[0][j] + accs[1][j] * accs[1][j]
             + accs[2][j] * accs[2][j] + accs[3][j] * accs[3][j];
    #pragma unroll
    for (int m = 1; m <= 8; m <<= 1) {
      s  += __shfl_xor(s, m, 64);
      q2 += __shfl_xor(q2, m, 64);
    }
    float mu = s * (1.f / 64.f);
    mean[j] = mu;
    rstd[j] = rsqrtf(q2 * (1.f / 64.f) - mu * mu + kEps);
  }

  const size_t gbase = rbase + 2048 + h * 64;
  const size_t obase = ((size_t)b * Lq + (size_t)chunk * CHK) * 1024 + h * 64;
  #pragma unroll
  for (int ej = 0; ej < 4; ++ej) {
    int e = 16 * ej + (l & 15);
    #pragma unroll
    for (int j = 0; j < 4; ++j) {
      int t = 16 * w + tl0 + j;
      float gate = bf2f(qkv[gbase + (size_t)t * QKVS + e]);
      float y = (accs[ej][j] - mean[j]) * rstd[j];
      gated[obase + (size_t)t * 1024 + e] = f2bf(gate * y);
    }
  }
}

} // namespace

extern "C" void kernel_launch(void* const* d_in, const int* in_sizes, int n_in,
                              void* d_out, int out_size, void* d_ws, size_t ws_size,
                              hipStream_t stream)
{
  (void)in_sizes; (void)n_in; (void)out_size; (void)ws_size;
  const float* x   = (const float*)d_in[0];
  const float* Wq  = (const float*)d_in[1];
  const float* Wk  = (const float*)d_in[2];
  const float* Wg1 = (const float*)d_in[3];
  const float* Wg2 = (const float*)d_in[4];
  const float* Wv  = (const float*)d_in[5];
  const float* Wg  = (const float*)d_in[6];
  const float* bg  = (const float*)d_in[7];
  const float* Wo  = (const float*)d_in[8];

  // workspace: 211.3 MB total
  char* w = (char*)d_ws;
  unsigned short* xh   = (unsigned short*)w; w += (size_t)Mrows * 1024 * 2;
  unsigned short* qkvg = (unsigned short*)w; w += (size_t)Mrows * QKVS * 2;
  float*  lgb = (float*)w;                   w += (size_t)Mrows * 512 * 4;
  float*  t1  = (float*)w;                   w += (size_t)Mrows * 16 * 4;
  float*  Pst = (float*)w;                   w += (size_t)64 * NCHK * 2048 * 4;
  float*  Dd  = (float*)w;                   w += (size_t)64 * NCHK * 32 * 4;
  unsigned short* Wqkvgt = (unsigned short*)w; w += (size_t)QKVS * 1024 * 2;
  unsigned short* Wot    = (unsigned short*)w; w += (size_t)1024 * 1024 * 2;
  unsigned short* gated  = xh;   // alias: xh dead after proj GEMM + gemm_g1

  cvt_bf16<<<2048, 256, 0, stream>>>(x, xh, Mrows * 1024 / 4);
  // batched weight conversion: Wq|Wk(scaled)|Wv|Wg -> Wqkvgt rows, Wo -> Wot
  CvtArgs ca;
  ca.W[0] = Wq;  ca.Wt[0] = Wqkvgt;                        ca.N[0] = 512;  ca.scale[0] = 1.f;    ca.start[0] = 0;   ca.nb[0] = 8;
  ca.W[1] = Wk;  ca.Wt[1] = Wqkvgt + (size_t)512 * 1024;   ca.N[1] = 512;  ca.scale[1] = kScale; ca.start[1] = 128; ca.nb[1] = 8;
  ca.W[2] = Wv;  ca.Wt[2] = Wqkvgt + (size_t)1024 * 1024;  ca.N[2] = 1024; ca.scale[2] = 1.f;    ca.start[2] = 256; ca.nb[2] = 16;
  ca.W[3] = Wg;  ca.Wt[3] = Wqkvgt + (size_t)2048 * 1024;  ca.N[3] = 1024; ca.scale[3] = 1.f;    ca.start[3] = 512; ca.nb[3] = 16;
  ca.W[4] = Wo;  ca.Wt[4] = Wot;                           ca.N[4] = 1024; ca.scale[4] = 1.f;    ca.start[4] = 768; ca.nb[4] = 16;
  cvt_w_all<<<1024, 256, 0, stream>>>(ca);
  // fused q|k|v|gate projection (R11-verified 256^2 MFMA)
  gemm256<2><<<dim3(12, 64), 512, 0, stream>>>(xh, Wqkvgt, bg, qkvg, QKVS);
  gemm_g1<<<Mrows / 16, 256, 0, stream>>>(xh, Wg1, t1);
  gemm_g2<<<(Mrows * 512) / 256, 256, 0, stream>>>(t1, Wg2, lgb);
  // chunked recurrence (MFMA) + fused gnorm/gate epilogue
  gla_chunk_state<<<64 * NCHK, 256, 0, stream>>>(qkvg, lgb, Pst, Dd);
  gla_chain<<<64, 256, 0, stream>>>(Pst, Dd);
  gla_chunk_out<<<64 * NCHK, 256, 0, stream>>>(qkvg, lgb, Pst, gated);
  // output projection (fp32 out)
  gemm256<3><<<dim3(4, 64), 512, 0, stream>>>(gated, Wot, nullptr, d_out, 1024);
}

// Round 16
// 344.299 us; speedup vs baseline: 1.2749x; 1.0429x over previous
//
#include <hip/hip_runtime.h>
#include <cstdint>

namespace {

constexpr int Lq  = 4096;
constexpr int Bq  = 4;
constexpr int H_  = 16;
constexpr int Mrows = Bq * Lq;               // 16384
constexpr int CHK  = 64;
constexpr int NCHK = Lq / CHK;               // 64
constexpr int QKVS = 3072;                   // fused q|k|v|gate row stride
constexpr float kScale = 0.17677669529663687f;  // 32^-0.5
constexpr float kEps   = 1e-5f;

typedef __attribute__((ext_vector_type(8))) short short8;
typedef __attribute__((ext_vector_type(4))) float f32x4;

__device__ __forceinline__ float bf2f(unsigned short u) {
  return __uint_as_float(((unsigned)u) << 16);
}
__device__ __forceinline__ unsigned short f2bf(float f) {
  unsigned u = __float_as_uint(f);
  u += 0x7fffu + ((u >> 16) & 1u);   // RNE
  return (unsigned short)(u >> 16);
}
__device__ __forceinline__ void gload_lds16(const void* g, void* l) {
  __builtin_amdgcn_global_load_lds(
      (const __attribute__((address_space(1))) void*)g,
      (__attribute__((address_space(3))) void*)l, 16, 0, 0);
}

// ---------- x fp32 -> bf16 ----------
__global__ __launch_bounds__(256)
void cvt_bf16(const float* __restrict__ in, unsigned short* __restrict__ out, int n4)
{
  int i = blockIdx.x * 256 + threadIdx.x;
  const int stride = gridDim.x * 256;
  for (; i < n4; i += stride) {
    float4 f = ((const float4*)in)[i];
    ushort4 u = make_ushort4(f2bf(f.x), f2bf(f.y), f2bf(f.z), f2bf(f.w));
    ((ushort4*)out)[i] = u;
  }
}

// ---------- batched W[K,N] fp32 -> Wt[N,K] bf16 (5 weights, 1 dispatch) ----------
struct CvtArgs {
  const float* W[5];
  unsigned short* Wt[5];
  int   N[5];
  float scale[5];
  int   start[5];
  int   nb[5];
};

__global__ __launch_bounds__(256)
void cvt_w_all(CvtArgs a)
{
  __shared__ float T[64][65];
  const int tid = threadIdx.x;
  const int b = blockIdx.x;
  int seg = 0;
  #pragma unroll
  for (int i = 1; i < 5; ++i) seg += (b >= a.start[i]) ? 1 : 0;
  const float* W = a.W[seg];
  unsigned short* Wt = a.Wt[seg];
  const int N = a.N[seg];
  const float scale = a.scale[seg];
  const int lb = b - a.start[seg];
  const int n0 = (lb % a.nb[seg]) * 64;
  const int k0 = (lb / a.nb[seg]) * 64;

  #pragma unroll
  for (int it = 0; it < 4; ++it) {
    int kr = (tid >> 4) + it * 16;
    float4 f = *(const float4*)(W + (size_t)(k0 + kr) * N + n0 + (tid & 15) * 4);
    T[kr][(tid & 15) * 4 + 0] = f.x;
    T[kr][(tid & 15) * 4 + 1] = f.y;
    T[kr][(tid & 15) * 4 + 2] = f.z;
    T[kr][(tid & 15) * 4 + 3] = f.w;
  }
  __syncthreads();
  #pragma unroll
  for (int it = 0; it < 4; ++it) {
    int nr = (tid >> 4) + it * 16;
    int c0 = (tid & 15) * 4;
    ushort4 u = make_ushort4(f2bf(T[c0 + 0][nr] * scale), f2bf(T[c0 + 1][nr] * scale),
                             f2bf(T[c0 + 2][nr] * scale), f2bf(T[c0 + 3][nr] * scale));
    *(ushort4*)(Wt + (size_t)(n0 + nr) * 1024 + k0 + c0) = u;
  }
}

// ========== 256x256 8-wave bf16 GEMM, K=1024, 1 barrier/K-tile ==========
// (R11 verified best: 157 us @ N=3072.)
// EPI: 2 = silu(x+bias[col-2048]) for col>=2048, store bf16
//      3 = plain, store fp32
template<int EPI>
__global__ __launch_bounds__(512, 1)
void gemm256(const unsigned short* __restrict__ A,
             const unsigned short* __restrict__ Bt,
             const float* __restrict__ bias,
             void* __restrict__ Cout, int N)
{
  __shared__ __align__(16) unsigned short As[2][256 * 64];
  __shared__ __align__(16) unsigned short Bs[2][256 * 64];
  const int tid = threadIdx.x;
  const int w = tid >> 6, l = tid & 63;
  const int wm = w >> 2, wn = w & 3;

  const int nbx = gridDim.x;
  const int bid = blockIdx.y * nbx + blockIdx.x;
  const int xcd = bid & 7;
  const int idx = bid >> 3;
  const int nsup = idx >> 4;           // 16 = 8 mPanels * 2 ni
  const int rem = idx & 15;
  const int mi = rem >> 1, ni = rem & 1;
  const int m0 = (xcd * 8 + mi) * 256;
  const int n0 = (nsup * 2 + ni) * 256;

  const int srow = tid >> 3;
  const int scol = ((tid & 7) ^ ((tid >> 3) & 7)) * 8;
  const unsigned short* gAp[4];
  const unsigned short* gBp[4];
  #pragma unroll
  for (int i = 0; i < 4; ++i) {
    gAp[i] = A  + (size_t)(m0 + i * 64 + srow) * 1024 + scol;
    gBp[i] = Bt + (size_t)(n0 + i * 64 + srow) * 1024 + scol;
  }

  const int rbA = wm * 128 + (l & 15);
  const int rbB = wn * 64 + (l & 15);
  const int swzA = (rbA & 7) << 4;
  const int swzB = (rbB & 7) << 4;
  const int colb = (l >> 4) * 16;

  f32x4 acc[8][4];
  #pragma unroll
  for (int i = 0; i < 8; ++i)
    #pragma unroll
    for (int j = 0; j < 4; ++j)
      acc[i][j] = (f32x4){0.f, 0.f, 0.f, 0.f};

  // prologue: stage tile 0 into buf 0
  #pragma unroll
  for (int i = 0; i < 4; ++i) {
    gload_lds16(gAp[i], (char*)&As[0][0] + i * 8192 + w * 1024);
    gload_lds16(gBp[i], (char*)&Bs[0][0] + i * 8192 + w * 1024);
    gAp[i] += 64; gBp[i] += 64;
  }

  int cur = 0;
  for (int t = 0; t < 16; ++t) {
    char* ldsA  = (char*)&As[cur][0];
    char* ldsB  = (char*)&Bs[cur][0];
    char* ldsAn = (char*)&As[cur ^ 1][0];
    char* ldsBn = (char*)&Bs[cur ^ 1][0];

    asm volatile("s_waitcnt vmcnt(0)" ::: "memory");
    __builtin_amdgcn_s_barrier();
    __builtin_amdgcn_sched_barrier(0);
    if (t < 15) {
      #pragma unroll
      for (int i = 0; i < 4; ++i) {
        gload_lds16(gAp[i], ldsAn + i * 8192 + w * 1024);
        gload_lds16(gBp[i], ldsBn + i * 8192 + w * 1024);
        gAp[i] += 64; gBp[i] += 64;
      }
    }

    #pragma unroll
    for (int ks = 0; ks < 2; ++ks) {
      short8 av[8], bv[4];
      #pragma unroll
      for (int mf = 0; mf < 8; ++mf) {
        int row = rbA + mf * 16;
        av[mf] = *(const short8*)(ldsA + row * 128 + ((ks * 64 + colb) ^ swzA));
      }
      #pragma unroll
      for (int nf = 0; nf < 4; ++nf) {
        int row = rbB + nf * 16;
        bv[nf] = *(const short8*)(ldsB + row * 128 + ((ks * 64 + colb) ^ swzB));
      }
      asm volatile("s_waitcnt lgkmcnt(0)" ::: "memory");
      __builtin_amdgcn_sched_barrier(0);
      __builtin_amdgcn_s_setprio(1);
      #pragma unroll
      for (int mf = 0; mf < 8; ++mf)
        #pragma unroll
        for (int nf = 0; nf < 4; ++nf)
          acc[mf][nf] = __builtin_amdgcn_mfma_f32_16x16x32_bf16(
              av[mf], bv[nf], acc[mf][nf], 0, 0, 0);
      __builtin_amdgcn_s_setprio(0);
    }
    cur ^= 1;
  }

  // epilogue
  const int cr = (l >> 4) * 4;
  const int cc = l & 15;
  #pragma unroll
  for (int mf = 0; mf < 8; ++mf) {
    #pragma unroll
    for (int nf = 0; nf < 4; ++nf) {
      int row = m0 + wm * 128 + mf * 16 + cr;
      int col = n0 + wn * 64 + nf * 16 + cc;
      #pragma unroll
      for (int j = 0; j < 4; ++j) {
        float x = acc[mf][nf][j];
        if (EPI == 2) {
          if (col >= 2048) {
            float z = x + bias[col - 2048];
            x = z / (1.f + expf(-z));
          }
        }
        if (EPI == 3)
          ((float*)Cout)[(size_t)(row + j) * N + col] = x;
        else
          ((unsigned short*)Cout)[(size_t)(row + j) * N + col] = f2bf(x);
      }
    }
  }
}

// ---------------- t1 = x_bf16[M,1024] @ Wg1[1024,16] (fp32 acc) ----------------
__global__ __launch_bounds__(256)
void gemm_g1(const unsigned short* __restrict__ x, const float* __restrict__ W1,
             float* __restrict__ t1)
{
  __shared__ float Xs[16][64];
  __shared__ float Ws[64][16];
  const int tid = threadIdx.x;
  const int m0 = blockIdx.x * 16;
  const int mi = tid >> 4, n = tid & 15;
  float acc = 0.f;
  for (int k0 = 0; k0 < 1024; k0 += 64) {
    ushort4 xv = *(const ushort4*)(x + (size_t)(m0 + (tid >> 4)) * 1024 + k0 + (tid & 15) * 4);
    Xs[tid >> 4][(tid & 15) * 4 + 0] = bf2f(xv.x);
    Xs[tid >> 4][(tid & 15) * 4 + 1] = bf2f(xv.y);
    Xs[tid >> 4][(tid & 15) * 4 + 2] = bf2f(xv.z);
    Xs[tid >> 4][(tid & 15) * 4 + 3] = bf2f(xv.w);
    *(float4*)&Ws[tid >> 2][(tid & 3) * 4] =
        *(const float4*)(W1 + (size_t)(k0 + (tid >> 2)) * 16 + (tid & 3) * 4);
    __syncthreads();
    #pragma unroll
    for (int kk = 0; kk < 64; ++kk)
      acc = fmaf(Xs[mi][kk], Ws[kk][n], acc);
    __syncthreads();
  }
  t1[(size_t)(m0 + mi) * 16 + n] = acc;
}

// --------- lg = log_sigmoid(t1 @ Wg2) / 16,  [M, 512] fp32 ---------
__global__ __launch_bounds__(256)
void gemm_g2(const float* __restrict__ t1, const float* __restrict__ W2,
             float* __restrict__ lg)
{
  const int idx = blockIdx.x * 256 + threadIdx.x;
  const int m = idx >> 9, n = idx & 511;
  float acc = 0.f;
  #pragma unroll
  for (int kk = 0; kk < 16; ++kk)
    acc = fmaf(t1[m * 16 + kk], W2[kk * 512 + n], acc);
  float ls = fminf(acc, 0.f) - log1pf(expf(-fabsf(acc)));
  lg[idx] = ls * 0.0625f;
}

// ============ chunked GLA — MFMA version (fused qkvg input) ============
// Parallel cumsum over t (serial depth 64 -> ~16): 8 groups of 8 rows;
// per-thread register partials -> group-prefix via LDS -> write back.
__global__ __launch_bounds__(256)
void gla_chunk_state(const unsigned short* __restrict__ qkv, const float* __restrict__ lg,
                     float* __restrict__ P, float* __restrict__ Dd)
{
  __shared__ __align__(16) float Lc[CHK][32];
  __shared__ float Gp[8][32];
  __shared__ __align__(16) unsigned short kdT[32][72];
  __shared__ __align__(16) unsigned short vT[64][72];
  const int blk = blockIdx.x;
  const int bh = blk >> 6, chunk = blk & (NCHK - 1);
  const int b = bh >> 4, h = bh & 15;
  const int tid = threadIdx.x;
  const int w = tid >> 6, l = tid & 63;
  const size_t rbase = ((size_t)b * Lq + (size_t)chunk * CHK) * QKVS;
  const size_t rowk = rbase + 512 + h * 32;
  const size_t rowv = rbase + 1024 + h * 64;
  const size_t rowl = ((size_t)b * Lq + (size_t)chunk * CHK) * 512 + h * 32;

  #pragma unroll
  for (int r = 0; r < 2; ++r) {
    int s4 = (tid + 256 * r) * 4;
    int t = s4 >> 5, d0 = s4 & 31;
    *(float4*)&Lc[t][d0] = *(const float4*)(lg + rowl + (size_t)t * 512 + d0);
  }
  __syncthreads();
  // parallel inclusive cumsum over t for each d
  {
    const int d = tid & 31, g = tid >> 5;
    float v[8];
    float s = 0.f;
    #pragma unroll
    for (int i = 0; i < 8; ++i) { v[i] = Lc[g * 8 + i][d]; s += v[i]; }
    Gp[g][d] = s;
    __syncthreads();
    float run = 0.f;
    for (int i = 0; i < g; ++i) run += Gp[i][d];
    #pragma unroll
    for (int i = 0; i < 8; ++i) { run += v[i]; Lc[g * 8 + i][d] = run; }
  }
  __syncthreads();
  #pragma unroll
  for (int r = 0; r < 2; ++r) {
    int s4 = (tid + 256 * r) * 4;
    int t = s4 >> 5, d0 = s4 & 31;
    ushort4 kv = *(const ushort4*)(qkv + rowk + (size_t)t * QKVS + d0);
    float4 lc = *(const float4*)&Lc[t][d0];
    float4 ls = *(const float4*)&Lc[CHK - 1][d0];
    kdT[d0 + 0][t] = f2bf(bf2f(kv.x) * expf(ls.x - lc.x));
    kdT[d0 + 1][t] = f2bf(bf2f(kv.y) * expf(ls.y - lc.y));
    kdT[d0 + 2][t] = f2bf(bf2f(kv.z) * expf(ls.z - lc.z));
    kdT[d0 + 3][t] = f2bf(bf2f(kv.w) * expf(ls.w - lc.w));
  }
  #pragma unroll
  for (int r = 0; r < 4; ++r) {
    int s4 = (tid + 256 * r) * 4;
    int t = s4 >> 6, e0 = s4 & 63;
    ushort4 vv = *(const ushort4*)(qkv + rowv + (size_t)t * QKVS + e0);
    vT[e0 + 0][t] = vv.x;
    vT[e0 + 1][t] = vv.y;
    vT[e0 + 2][t] = vv.z;
    vT[e0 + 3][t] = vv.w;
  }
  __syncthreads();
  #pragma unroll
  for (int dj = 0; dj < 2; ++dj) {
    f32x4 acc = (f32x4){0.f, 0.f, 0.f, 0.f};
    #pragma unroll
    for (int ks = 0; ks < 2; ++ks) {
      short8 aV = *(const short8*)((const char*)&vT[0][0] +
                    (16 * w + (l & 15)) * 144 + ks * 64 + (l >> 4) * 16);
      short8 bK = *(const short8*)((const char*)&kdT[0][0] +
                    (16 * dj + (l & 15)) * 144 + ks * 64 + (l >> 4) * 16);
      acc = __builtin_amdgcn_mfma_f32_16x16x32_bf16(aV, bK, acc, 0, 0, 0);
    }
    #pragma unroll
    for (int j = 0; j < 4; ++j) {
      int e = 16 * w + (l >> 4) * 4 + j;
      int d = 16 * dj + (l & 15);
      P[(size_t)blk * 2048 + e * 32 + d] = acc[j];
    }
  }
  if (tid < 32) Dd[(size_t)blk * 32 + tid] = expf(Lc[CHK - 1][tid]);
}

// chain over chunks per (bh, e-half); depth-4 prefetched (P[i+4] loads are
// independent of the running state -> ~4 round-trips in flight).
__global__ __launch_bounds__(256)
void gla_chain(float* __restrict__ P, const float* __restrict__ Dd)
{
  const int bh = blockIdx.x >> 1, half = blockIdx.x & 1;
  const int tid = threadIdx.x;
  const int f = tid * 4 + half * 1024;
  const int d0 = f & 31;
  const size_t pb = (size_t)bh * NCHK;
  float4 s = {0.f, 0.f, 0.f, 0.f};

  float4 p0 = *(const float4*)(P + (pb + 0) * 2048 + f);
  float4 p1 = *(const float4*)(P + (pb + 1) * 2048 + f);
  float4 p2 = *(const float4*)(P + (pb + 2) * 2048 + f);
  float4 p3 = *(const float4*)(P + (pb + 3) * 2048 + f);
  float4 g0 = *(const float4*)(Dd + (pb + 0) * 32 + d0);
  float4 g1 = *(const float4*)(Dd + (pb + 1) * 32 + d0);
  float4 g2 = *(const float4*)(Dd + (pb + 2) * 32 + d0);
  float4 g3 = *(const float4*)(Dd + (pb + 3) * 32 + d0);

  for (int i = 0; i < NCHK; i += 4) {
    *(float4*)(P + (pb + i) * 2048 + f) = s;
    s.x = fmaf(s.x, g0.x, p0.x); s.y = fmaf(s.y, g0.y, p0.y);
    s.z = fmaf(s.z, g0.z, p0.z); s.w = fmaf(s.w, g0.w, p0.w);
    if (i + 4 < NCHK) {
      p0 = *(const float4*)(P + (pb + i + 4) * 2048 + f);
      g0 = *(const float4*)(Dd + (pb + i + 4) * 32 + d0);
    }
    *(float4*)(P + (pb + i + 1) * 2048 + f) = s;
    s.x = fmaf(s.x, g1.x, p1.x); s.y = fmaf(s.y, g1.y, p1.y);
    s.z = fmaf(s.z, g1.z, p1.z); s.w = fmaf(s.w, g1.w, p1.w);
    if (i + 5 < NCHK) {
      p1 = *(const float4*)(P + (pb + i + 5) * 2048 + f);
      g1 = *(const float4*)(Dd + (pb + i + 5) * 32 + d0);
    }
    *(float4*)(P + (pb + i + 2) * 2048 + f) = s;
    s.x = fmaf(s.x, g2.x, p2.x); s.y = fmaf(s.y, g2.y, p2.y);
    s.z = fmaf(s.z, g2.z, p2.z); s.w = fmaf(s.w, g2.w, p2.w);
    if (i + 6 < NCHK) {
      p2 = *(const float4*)(P + (pb + i + 6) * 2048 + f);
      g2 = *(const float4*)(Dd + (pb + i + 6) * 32 + d0);
    }
    *(float4*)(P + (pb + i + 3) * 2048 + f) = s;
    s.x = fmaf(s.x, g3.x, p3.x); s.y = fmaf(s.y, g3.y, p3.y);
    s.z = fmaf(s.z, g3.z, p3.z); s.w = fmaf(s.w, g3.w, p3.w);
    if (i + 7 < NCHK) {
      p3 = *(const float4*)(P + (pb + i + 7) * 2048 + f);
      g3 = *(const float4*)(Dd + (pb + i + 7) * 32 + d0);
    }
  }
}

// chunk_out + fused group-norm + gate multiply -> bf16 gated [M][1024]
__global__ __launch_bounds__(256)
void gla_chunk_out(const unsigned short* __restrict__ qkv, const float* __restrict__ lg,
                   const float* __restrict__ S, unsigned short* __restrict__ gated)
{
  __shared__ __align__(16) float Lc[CHK][32];
  __shared__ float Gp[8][32];
  __shared__ __align__(16) unsigned short qb[CHK][40];
  __shared__ __align__(16) unsigned short kd[CHK][40];
  __shared__ __align__(16) unsigned short vT[64][72];
  __shared__ __align__(16) unsigned short ST[64][40];
  __shared__ __align__(16) unsigned short Aq[64][72];
  const int blk = blockIdx.x;
  const int bh = blk >> 6, chunk = blk & (NCHK - 1);
  const int b = bh >> 4, h = bh & 15;
  const int tid = threadIdx.x;
  const int w = tid >> 6, l = tid & 63;
  const size_t rbase = ((size_t)b * Lq + (size_t)chunk * CHK) * QKVS;
  const size_t rowq = rbase + h * 32;
  const size_t rowk = rbase + 512 + h * 32;
  const size_t rowv = rbase + 1024 + h * 64;
  const size_t rowl = ((size_t)b * Lq + (size_t)chunk * CHK) * 512 + h * 32;

  #pragma unroll
  for (int r = 0; r < 2; ++r) {
    int s4 = (tid + 256 * r) * 4;
    int t = s4 >> 5, d0 = s4 & 31;
    *(float4*)&Lc[t][d0] = *(const float4*)(lg + rowl + (size_t)t * 512 + d0);
  }
  __syncthreads();
  // parallel inclusive cumsum over t for each d
  {
    const int d = tid & 31, g = tid >> 5;
    float v[8];
    float s = 0.f;
    #pragma unroll
    for (int i = 0; i < 8; ++i) { v[i] = Lc[g * 8 + i][d]; s += v[i]; }
    Gp[g][d] = s;
    __syncthreads();
    float run = 0.f;
    for (int i = 0; i < g; ++i) run += Gp[i][d];
    #pragma unroll
    for (int i = 0; i < 8; ++i) { run += v[i]; Lc[g * 8 + i][d] = run; }
  }
  __syncthreads();
  #pragma unroll
  for (int r = 0; r < 2; ++r) {
    int s4 = (tid + 256 * r) * 4;
    int t = s4 >> 5, d0 = s4 & 31;
    ushort4 kv = *(const ushort4*)(qkv + rowk + (size_t)t * QKVS + d0);
    ushort4 qv = *(const ushort4*)(qkv + rowq + (size_t)t * QKVS + d0);
    float4 lc = *(const float4*)&Lc[t][d0];
    ushort4 ko, qo;
    ko.x = f2bf(bf2f(kv.x) * expf(-lc.x)); qo.x = f2bf(bf2f(qv.x) * expf(lc.x));
    ko.y = f2bf(bf2f(kv.y) * expf(-lc.y)); qo.y = f2bf(bf2f(qv.y) * expf(lc.y));
    ko.z = f2bf(bf2f(kv.z) * expf(-lc.z)); qo.z = f2bf(bf2f(qv.z) * expf(lc.z));
    ko.w = f2bf(bf2f(kv.w) * expf(-lc.w)); qo.w = f2bf(bf2f(qv.w) * expf(lc.w));
    *(ushort4*)&kd[t][d0] = ko;
    *(ushort4*)&qb[t][d0] = qo;
  }
  #pragma unroll
  for (int r = 0; r < 4; ++r) {
    int s4 = (tid + 256 * r) * 4;
    int t = s4 >> 6, e0 = s4 & 63;
    ushort4 vv = *(const ushort4*)(qkv + rowv + (size_t)t * QKVS + e0);
    vT[e0 + 0][t] = vv.x;
    vT[e0 + 1][t] = vv.y;
    vT[e0 + 2][t] = vv.z;
    vT[e0 + 3][t] = vv.w;
  }
  #pragma unroll
  for (int r = 0; r < 2; ++r) {
    int s4 = (tid + 256 * r) * 4;
    int e = s4 >> 5, d0 = s4 & 31;
    float4 f = *(const float4*)(S + (size_t)blk * 2048 + s4);
    ushort4 u = make_ushort4(f2bf(f.x), f2bf(f.y), f2bf(f.z), f2bf(f.w));
    *(ushort4*)&ST[e][d0] = u;
  }
  __syncthreads();

  short8 aQ = *(const short8*)((const char*)&qb[0][0] +
               (16 * w + (l & 15)) * 80 + (l >> 4) * 16);
  const int tl0 = (l >> 4) * 4;
  #pragma unroll
  for (int si = 0; si < 4; ++si) {
    if (si <= w) {
      short8 bK = *(const short8*)((const char*)&kd[0][0] +
                   (16 * si + (l & 15)) * 80 + (l >> 4) * 16);
      f32x4 acc = (f32x4){0.f, 0.f, 0.f, 0.f};
      acc = __builtin_amdgcn_mfma_f32_16x16x32_bf16(aQ, bK, acc, 0, 0, 0);
      #pragma unroll
      for (int j = 0; j < 4; ++j) {
        bool keep = (si < w) || ((l & 15) <= tl0 + j);
        Aq[16 * w + tl0 + j][16 * si + (l & 15)] = keep ? f2bf(acc[j]) : 0;
      }
    } else {
      #pragma unroll
      for (int j = 0; j < 4; ++j)
        Aq[16 * w + tl0 + j][16 * si + (l & 15)] = 0;
    }
  }
  __syncthreads();

  short8 aA0 = *(const short8*)((const char*)&Aq[0][0] +
                (16 * w + (l & 15)) * 144 + (l >> 4) * 16);
  short8 aA1 = *(const short8*)((const char*)&Aq[0][0] +
                (16 * w + (l & 15)) * 144 + 64 + (l >> 4) * 16);
  f32x4 accs[4];
  #pragma unroll
  for (int ej = 0; ej < 4; ++ej) {
    f32x4 acc = (f32x4){0.f, 0.f, 0.f, 0.f};
    short8 bV0 = *(const short8*)((const char*)&vT[0][0] +
                  (16 * ej + (l & 15)) * 144 + (l >> 4) * 16);
    short8 bV1 = *(const short8*)((const char*)&vT[0][0] +
                  (16 * ej + (l & 15)) * 144 + 64 + (l >> 4) * 16);
    short8 bS = *(const short8*)((const char*)&ST[0][0] +
                  (16 * ej + (l & 15)) * 80 + (l >> 4) * 16);
    acc = __builtin_amdgcn_mfma_f32_16x16x32_bf16(aA0, bV0, acc, 0, 0, 0);
    acc = __builtin_amdgcn_mfma_f32_16x16x32_bf16(aA1, bV1, acc, 0, 0, 0);
    acc = __builtin_amdgcn_mfma_f32_16x16x32_bf16(aQ,  bS,  acc, 0, 0, 0);
    accs[ej] = acc;
  }

  float mean[4], rstd[4];
  #pragma unroll
  for (int j = 0; j < 4; ++j) {
    float s  = accs[0][j] + accs[1][j] + accs[2][j] + accs[3][j];
    float q2 = accs[0][j] * accs[0][j] + accs[1][j] * accs[1][j]
             + accs[2][j] * accs[2][j] + accs[3][j] * accs[3][j];
    #pragma unroll
    for (int m = 1; m <= 8; m <<= 1) {
      s  += __shfl_xor(s, m, 64);
      q2 += __shfl_xor(q2, m, 64);
    }
    float mu = s * (1.f / 64.f);
    mean[j] = mu;
    rstd[j] = rsqrtf(q2 * (1.f / 64.f) - mu * mu + kEps);
  }

  const size_t gbase = rbase + 2048 + h * 64;
  const size_t obase = ((size_t)b * Lq + (size_t)chunk * CHK) * 1024 + h * 64;
  #pragma unroll
  for (int ej = 0; ej < 4; ++ej) {
    int e = 16 * ej + (l & 15);
    #pragma unroll
    for (int j = 0; j < 4; ++j) {
      int t = 16 * w + tl0 + j;
      float gate = bf2f(qkv[gbase + (size_t)t * QKVS + e]);
      float y = (accs[ej][j] - mean[j]) * rstd[j];
      gated[obase + (size_t)t * 1024 + e] = f2bf(gate * y);
    }
  }
}

} // namespace

extern "C" void kernel_launch(void* const* d_in, const int* in_sizes, int n_in,
                              void* d_out, int out_size, void* d_ws, size_t ws_size,
                              hipStream_t stream)
{
  (void)in_sizes; (void)n_in; (void)out_size; (void)ws_size;
  const float* x   = (const float*)d_in[0];
  const float* Wq  = (const float*)d_in[1];
  const float* Wk  = (const float*)d_in[2];
  const float* Wg1 = (const float*)d_in[3];
  const float* Wg2 = (const float*)d_in[4];
  const float* Wv  = (const float*)d_in[5];
  const float* Wg  = (const float*)d_in[6];
  const float* bg  = (const float*)d_in[7];
  const float* Wo  = (const float*)d_in[8];

  // workspace: 211.3 MB total
  char* w = (char*)d_ws;
  unsigned short* xh   = (unsigned short*)w; w += (size_t)Mrows * 1024 * 2;
  unsigned short* qkvg = (unsigned short*)w; w += (size_t)Mrows * QKVS * 2;
  float*  lgb = (float*)w;                   w += (size_t)Mrows * 512 * 4;
  float*  t1  = (float*)w;                   w += (size_t)Mrows * 16 * 4;
  float*  Pst = (float*)w;                   w += (size_t)64 * NCHK * 2048 * 4;
  float*  Dd  = (float*)w;                   w += (size_t)64 * NCHK * 32 * 4;
  unsigned short* Wqkvgt = (unsigned short*)w; w += (size_t)QKVS * 1024 * 2;
  unsigned short* Wot    = (unsigned short*)w; w += (size_t)1024 * 1024 * 2;
  unsigned short* gated  = xh;   // alias: xh dead after proj GEMM + gemm_g1

  cvt_bf16<<<2048, 256, 0, stream>>>(x, xh, Mrows * 1024 / 4);
  CvtArgs ca;
  ca.W[0] = Wq;  ca.Wt[0] = Wqkvgt;                        ca.N[0] = 512;  ca.scale[0] = 1.f;    ca.start[0] = 0;   ca.nb[0] = 8;
  ca.W[1] = Wk;  ca.Wt[1] = Wqkvgt + (size_t)512 * 1024;   ca.N[1] = 512;  ca.scale[1] = kScale; ca.start[1] = 128; ca.nb[1] = 8;
  ca.W[2] = Wv;  ca.Wt[2] = Wqkvgt + (size_t)1024 * 1024;  ca.N[2] = 1024; ca.scale[2] = 1.f;    ca.start[2] = 256; ca.nb[2] = 16;
  ca.W[3] = Wg;  ca.Wt[3] = Wqkvgt + (size_t)2048 * 1024;  ca.N[3] = 1024; ca.scale[3] = 1.f;    ca.start[3] = 512; ca.nb[3] = 16;
  ca.W[4] = Wo;  ca.Wt[4] = Wot;                           ca.N[4] = 1024; ca.scale[4] = 1.f;    ca.start[4] = 768; ca.nb[4] = 16;
  cvt_w_all<<<1024, 256, 0, stream>>>(ca);
  // fused q|k|v|gate projection (R11-verified 256^2 MFMA)
  gemm256<2><<<dim3(12, 64), 512, 0, stream>>>(xh, Wqkvgt, bg, qkvg, QKVS);
  gemm_g1<<<Mrows / 16, 256, 0, stream>>>(xh, Wg1, t1);
  gemm_g2<<<(Mrows * 512) / 256, 256, 0, stream>>>(t1, Wg2, lgb);
  // chunked recurrence (MFMA) + fused gnorm/gate epilogue
  gla_chunk_state<<<64 * NCHK, 256, 0, stream>>>(qkvg, lgb, Pst, Dd);
  gla_chain<<<128, 256, 0, stream>>>(Pst, Dd);
  gla_chunk_out<<<64 * NCHK, 256, 0, stream>>>(qkvg, lgb, Pst, gated);
  // output projection (fp32 out)
  gemm256<3><<<dim3(4, 64), 512, 0, stream>>>(gated, Wot, nullptr, d_out, 1024);
}

// Round 17
// 330.899 us; speedup vs baseline: 1.3265x; 1.0405x over previous
//
#include <hip/hip_runtime.h>
#include <cstdint>

namespace {

constexpr int Lq  = 4096;
constexpr int Bq  = 4;
constexpr int H_  = 16;
constexpr int Mrows = Bq * Lq;               // 16384
constexpr int CHK  = 64;
constexpr int NCHK = Lq / CHK;               // 64
constexpr int QKVS = 3072;                   // fused q|k|v|gate row stride
constexpr float kScale = 0.17677669529663687f;  // 32^-0.5
constexpr float kEps   = 1e-5f;

typedef __attribute__((ext_vector_type(8))) short short8;
typedef __attribute__((ext_vector_type(4))) float f32x4;

__device__ __forceinline__ float bf2f(unsigned short u) {
  return __uint_as_float(((unsigned)u) << 16);
}
__device__ __forceinline__ unsigned short f2bf(float f) {
  unsigned u = __float_as_uint(f);
  u += 0x7fffu + ((u >> 16) & 1u);   // RNE
  return (unsigned short)(u >> 16);
}
__device__ __forceinline__ void gload_lds16(const void* g, void* l) {
  __builtin_amdgcn_global_load_lds(
      (const __attribute__((address_space(1))) void*)g,
      (__attribute__((address_space(3))) void*)l, 16, 0, 0);
}

// ---------- x fp32 -> bf16 ----------
__global__ __launch_bounds__(256)
void cvt_bf16(const float* __restrict__ in, unsigned short* __restrict__ out, int n4)
{
  int i = blockIdx.x * 256 + threadIdx.x;
  const int stride = gridDim.x * 256;
  for (; i < n4; i += stride) {
    float4 f = ((const float4*)in)[i];
    ushort4 u = make_ushort4(f2bf(f.x), f2bf(f.y), f2bf(f.z), f2bf(f.w));
    ((ushort4*)out)[i] = u;
  }
}

// ---------- batched W[K,N] fp32 -> Wt[N,K] bf16 (5 weights, 1 dispatch) ----------
struct CvtArgs {
  const float* W[5];
  unsigned short* Wt[5];
  int   N[5];
  float scale[5];
  int   start[5];
  int   nb[5];
};

__global__ __launch_bounds__(256)
void cvt_w_all(CvtArgs a)
{
  __shared__ float T[64][65];
  const int tid = threadIdx.x;
  const int b = blockIdx.x;
  int seg = 0;
  #pragma unroll
  for (int i = 1; i < 5; ++i) seg += (b >= a.start[i]) ? 1 : 0;
  const float* W = a.W[seg];
  unsigned short* Wt = a.Wt[seg];
  const int N = a.N[seg];
  const float scale = a.scale[seg];
  const int lb = b - a.start[seg];
  const int n0 = (lb % a.nb[seg]) * 64;
  const int k0 = (lb / a.nb[seg]) * 64;

  #pragma unroll
  for (int it = 0; it < 4; ++it) {
    int kr = (tid >> 4) + it * 16;
    float4 f = *(const float4*)(W + (size_t)(k0 + kr) * N + n0 + (tid & 15) * 4);
    T[kr][(tid & 15) * 4 + 0] = f.x;
    T[kr][(tid & 15) * 4 + 1] = f.y;
    T[kr][(tid & 15) * 4 + 2] = f.z;
    T[kr][(tid & 15) * 4 + 3] = f.w;
  }
  __syncthreads();
  #pragma unroll
  for (int it = 0; it < 4; ++it) {
    int nr = (tid >> 4) + it * 16;
    int c0 = (tid & 15) * 4;
    ushort4 u = make_ushort4(f2bf(T[c0 + 0][nr] * scale), f2bf(T[c0 + 1][nr] * scale),
                             f2bf(T[c0 + 2][nr] * scale), f2bf(T[c0 + 3][nr] * scale));
    *(ushort4*)(Wt + (size_t)(n0 + nr) * 1024 + k0 + c0) = u;
  }
}

// ==== 256x256 8-wave bf16 GEMM, K=1024: 4-slot half-tile ring, counted vmcnt ====
// Slots hold K-halves (A[256][32] + B[256][32] = 32 KB); ring of 4.
// Per half-step: vmcnt(8) [2 halves stay in flight] -> barrier -> issue 4
// loads for half h+3 -> 12 ds_read (each fragment once) -> lgkmcnt(0) ->
// 32 MFMA. Loads are ~2.5 half-steps stale at their wait (T4 counted-vmcnt).
// EPI: 2 = silu(x+bias[col-2048]) for col>=2048, store bf16
//      3 = plain, store fp32
template<int EPI>
__global__ __launch_bounds__(512, 1)
void gemm256(const unsigned short* __restrict__ A,
             const unsigned short* __restrict__ Bt,
             const float* __restrict__ bias,
             void* __restrict__ Cout, int N)
{
  __shared__ __align__(16) unsigned short Buf[4][16384];   // 4 x 32 KB
  const int tid = threadIdx.x;
  const int w = tid >> 6, l = tid & 63;
  const int wm = w >> 2, wn = w & 3;

  const int nbx = gridDim.x;
  const int bid = blockIdx.y * nbx + blockIdx.x;
  const int xcd = bid & 7;
  const int idx = bid >> 3;
  const int nsup = idx >> 4;           // 16 = 8 mPanels * 2 ni
  const int rem = idx & 15;
  const int mi = rem >> 1, ni = rem & 1;
  const int m0 = (xcd * 8 + mi) * 256;
  const int n0 = (nsup * 2 + ni) * 256;

  // staging: per load, 512 threads x 16B cover 128 rows x 64B (32 bf16).
  // source col pre-swizzled so LDS[r][c16] holds k-group c16 ^ ((r>>1)&3).
  const int srow = tid >> 2;                             // 0..127
  const int scol = ((tid & 3) ^ ((tid >> 3) & 3)) * 8;   // pre-swizzled k8-group
  const unsigned short* gA0 = A  + (size_t)(m0 + srow) * 1024 + scol;
  const unsigned short* gA1 = A  + (size_t)(m0 + 128 + srow) * 1024 + scol;
  const unsigned short* gB0 = Bt + (size_t)(n0 + srow) * 1024 + scol;
  const unsigned short* gB1 = Bt + (size_t)(n0 + 128 + srow) * 1024 + scol;

  // read-side: row r, k-group g=l>>4 -> byte r*64 + ((g ^ ((r>>1)&3))<<4);
  // ((r>>1)&3) reduces to (((l&15)>>1)&3) for both A and B row bases.
  const int rbA = wm * 128 + (l & 15);
  const int rbB = wn * 64 + (l & 15);
  const int sw = (((((l & 15) >> 1) & 3) ^ (l >> 4)) << 4);

  f32x4 acc[8][4];
  #pragma unroll
  for (int i = 0; i < 8; ++i)
    #pragma unroll
    for (int j = 0; j < 4; ++j)
      acc[i][j] = (f32x4){0.f, 0.f, 0.f, 0.f};

  // prologue: issue halves 0,1,2 (12 loads in flight)
  #pragma unroll
  for (int h = 0; h < 3; ++h) {
    char* dst = (char*)&Buf[h][0] + w * 1024;
    gload_lds16(gA0, dst);
    gload_lds16(gA1, dst + 8192);
    gload_lds16(gB0, dst + 16384);
    gload_lds16(gB1, dst + 24576);
    gA0 += 32; gA1 += 32; gB0 += 32; gB1 += 32;
  }

  for (int h = 0; h < 32; ++h) {
    if (h < 30)       asm volatile("s_waitcnt vmcnt(8)" ::: "memory");
    else if (h == 30) asm volatile("s_waitcnt vmcnt(4)" ::: "memory");
    else              asm volatile("s_waitcnt vmcnt(0)" ::: "memory");
    __builtin_amdgcn_s_barrier();
    __builtin_amdgcn_sched_barrier(0);

    if (h + 3 < 32) {
      char* dst = (char*)&Buf[(h + 3) & 3][0] + w * 1024;
      gload_lds16(gA0, dst);
      gload_lds16(gA1, dst + 8192);
      gload_lds16(gB0, dst + 16384);
      gload_lds16(gB1, dst + 24576);
      gA0 += 32; gA1 += 32; gB0 += 32; gB1 += 32;
    }

    char* ldsA = (char*)&Buf[h & 3][0];
    char* ldsB = ldsA + 16384;
    short8 av[8], bv[4];
    #pragma unroll
    for (int mf = 0; mf < 8; ++mf)
      av[mf] = *(const short8*)(ldsA + (rbA + mf * 16) * 64 + sw);
    #pragma unroll
    for (int nf = 0; nf < 4; ++nf)
      bv[nf] = *(const short8*)(ldsB + (rbB + nf * 16) * 64 + sw);
    asm volatile("s_waitcnt lgkmcnt(0)" ::: "memory");
    __builtin_amdgcn_sched_barrier(0);
    __builtin_amdgcn_s_setprio(1);
    #pragma unroll
    for (int mf = 0; mf < 8; ++mf)
      #pragma unroll
      for (int nf = 0; nf < 4; ++nf)
        acc[mf][nf] = __builtin_amdgcn_mfma_f32_16x16x32_bf16(
            av[mf], bv[nf], acc[mf][nf], 0, 0, 0);
    __builtin_amdgcn_s_setprio(0);
  }

  // epilogue
  const int cr = (l >> 4) * 4;
  const int cc = l & 15;
  #pragma unroll
  for (int mf = 0; mf < 8; ++mf) {
    #pragma unroll
    for (int nf = 0; nf < 4; ++nf) {
      int row = m0 + wm * 128 + mf * 16 + cr;
      int col = n0 + wn * 64 + nf * 16 + cc;
      #pragma unroll
      for (int j = 0; j < 4; ++j) {
        float x = acc[mf][nf][j];
        if (EPI == 2) {
          if (col >= 2048) {
            float z = x + bias[col - 2048];
            x = z / (1.f + expf(-z));
          }
        }
        if (EPI == 3)
          ((float*)Cout)[(size_t)(row + j) * N + col] = x;
        else
          ((unsigned short*)Cout)[(size_t)(row + j) * N + col] = f2bf(x);
      }
    }
  }
}

// ---------------- t1 = x_bf16[M,1024] @ Wg1[1024,16] (fp32 acc) ----------------
__global__ __launch_bounds__(256)
void gemm_g1(const unsigned short* __restrict__ x, const float* __restrict__ W1,
             float* __restrict__ t1)
{
  __shared__ float Xs[16][64];
  __shared__ float Ws[64][16];
  const int tid = threadIdx.x;
  const int m0 = blockIdx.x * 16;
  const int mi = tid >> 4, n = tid & 15;
  float acc = 0.f;
  for (int k0 = 0; k0 < 1024; k0 += 64) {
    ushort4 xv = *(const ushort4*)(x + (size_t)(m0 + (tid >> 4)) * 1024 + k0 + (tid & 15) * 4);
    Xs[tid >> 4][(tid & 15) * 4 + 0] = bf2f(xv.x);
    Xs[tid >> 4][(tid & 15) * 4 + 1] = bf2f(xv.y);
    Xs[tid >> 4][(tid & 15) * 4 + 2] = bf2f(xv.z);
    Xs[tid >> 4][(tid & 15) * 4 + 3] = bf2f(xv.w);
    *(float4*)&Ws[tid >> 2][(tid & 3) * 4] =
        *(const float4*)(W1 + (size_t)(k0 + (tid >> 2)) * 16 + (tid & 3) * 4);
    __syncthreads();
    #pragma unroll
    for (int kk = 0; kk < 64; ++kk)
      acc = fmaf(Xs[mi][kk], Ws[kk][n], acc);
    __syncthreads();
  }
  t1[(size_t)(m0 + mi) * 16 + n] = acc;
}

// --------- lg = log_sigmoid(t1 @ Wg2) / 16,  [M, 512] fp32 ---------
__global__ __launch_bounds__(256)
void gemm_g2(const float* __restrict__ t1, const float* __restrict__ W2,
             float* __restrict__ lg)
{
  const int idx = blockIdx.x * 256 + threadIdx.x;
  const int m = idx >> 9, n = idx & 511;
  float acc = 0.f;
  #pragma unroll
  for (int kk = 0; kk < 16; ++kk)
    acc = fmaf(t1[m * 16 + kk], W2[kk * 512 + n], acc);
  float ls = fminf(acc, 0.f) - log1pf(expf(-fabsf(acc)));
  lg[idx] = ls * 0.0625f;
}

// ============ chunked GLA — MFMA version (fused qkvg input) ============
__global__ __launch_bounds__(256)
void gla_chunk_state(const unsigned short* __restrict__ qkv, const float* __restrict__ lg,
                     float* __restrict__ P, float* __restrict__ Dd)
{
  __shared__ __align__(16) float Lc[CHK][32];
  __shared__ float Gp[8][32];
  __shared__ __align__(16) unsigned short kdT[32][72];
  __shared__ __align__(16) unsigned short vT[64][72];
  const int blk = blockIdx.x;
  const int bh = blk >> 6, chunk = blk & (NCHK - 1);
  const int b = bh >> 4, h = bh & 15;
  const int tid = threadIdx.x;
  const int w = tid >> 6, l = tid & 63;
  const size_t rbase = ((size_t)b * Lq + (size_t)chunk * CHK) * QKVS;
  const size_t rowk = rbase + 512 + h * 32;
  const size_t rowv = rbase + 1024 + h * 64;
  const size_t rowl = ((size_t)b * Lq + (size_t)chunk * CHK) * 512 + h * 32;

  #pragma unroll
  for (int r = 0; r < 2; ++r) {
    int s4 = (tid + 256 * r) * 4;
    int t = s4 >> 5, d0 = s4 & 31;
    *(float4*)&Lc[t][d0] = *(const float4*)(lg + rowl + (size_t)t * 512 + d0);
  }
  __syncthreads();
  {
    const int d = tid & 31, g = tid >> 5;
    float v[8];
    float s = 0.f;
    #pragma unroll
    for (int i = 0; i < 8; ++i) { v[i] = Lc[g * 8 + i][d]; s += v[i]; }
    Gp[g][d] = s;
    __syncthreads();
    float run = 0.f;
    for (int i = 0; i < g; ++i) run += Gp[i][d];
    #pragma unroll
    for (int i = 0; i < 8; ++i) { run += v[i]; Lc[g * 8 + i][d] = run; }
  }
  __syncthreads();
  #pragma unroll
  for (int r = 0; r < 2; ++r) {
    int s4 = (tid + 256 * r) * 4;
    int t = s4 >> 5, d0 = s4 & 31;
    ushort4 kv = *(const ushort4*)(qkv + rowk + (size_t)t * QKVS + d0);
    float4 lc = *(const float4*)&Lc[t][d0];
    float4 ls = *(const float4*)&Lc[CHK - 1][d0];
    kdT[d0 + 0][t] = f2bf(bf2f(kv.x) * expf(ls.x - lc.x));
    kdT[d0 + 1][t] = f2bf(bf2f(kv.y) * expf(ls.y - lc.y));
    kdT[d0 + 2][t] = f2bf(bf2f(kv.z) * expf(ls.z - lc.z));
    kdT[d0 + 3][t] = f2bf(bf2f(kv.w) * expf(ls.w - lc.w));
  }
  #pragma unroll
  for (int r = 0; r < 4; ++r) {
    int s4 = (tid + 256 * r) * 4;
    int t = s4 >> 6, e0 = s4 & 63;
    ushort4 vv = *(const ushort4*)(qkv + rowv + (size_t)t * QKVS + e0);
    vT[e0 + 0][t] = vv.x;
    vT[e0 + 1][t] = vv.y;
    vT[e0 + 2][t] = vv.z;
    vT[e0 + 3][t] = vv.w;
  }
  __syncthreads();
  #pragma unroll
  for (int dj = 0; dj < 2; ++dj) {
    f32x4 acc = (f32x4){0.f, 0.f, 0.f, 0.f};
    #pragma unroll
    for (int ks = 0; ks < 2; ++ks) {
      short8 aV = *(const short8*)((const char*)&vT[0][0] +
                    (16 * w + (l & 15)) * 144 + ks * 64 + (l >> 4) * 16);
      short8 bK = *(const short8*)((const char*)&kdT[0][0] +
                    (16 * dj + (l & 15)) * 144 + ks * 64 + (l >> 4) * 16);
      acc = __builtin_amdgcn_mfma_f32_16x16x32_bf16(aV, bK, acc, 0, 0, 0);
    }
    #pragma unroll
    for (int j = 0; j < 4; ++j) {
      int e = 16 * w + (l >> 4) * 4 + j;
      int d = 16 * dj + (l & 15);
      P[(size_t)blk * 2048 + e * 32 + d] = acc[j];
    }
  }
  if (tid < 32) Dd[(size_t)blk * 32 + tid] = expf(Lc[CHK - 1][tid]);
}

// chain over chunks per (bh, e-half); depth-4 prefetched.
__global__ __launch_bounds__(256)
void gla_chain(float* __restrict__ P, const float* __restrict__ Dd)
{
  const int bh = blockIdx.x >> 1, half = blockIdx.x & 1;
  const int tid = threadIdx.x;
  const int f = tid * 4 + half * 1024;
  const int d0 = f & 31;
  const size_t pb = (size_t)bh * NCHK;
  float4 s = {0.f, 0.f, 0.f, 0.f};

  float4 p0 = *(const float4*)(P + (pb + 0) * 2048 + f);
  float4 p1 = *(const float4*)(P + (pb + 1) * 2048 + f);
  float4 p2 = *(const float4*)(P + (pb + 2) * 2048 + f);
  float4 p3 = *(const float4*)(P + (pb + 3) * 2048 + f);
  float4 g0 = *(const float4*)(Dd + (pb + 0) * 32 + d0);
  float4 g1 = *(const float4*)(Dd + (pb + 1) * 32 + d0);
  float4 g2 = *(const float4*)(Dd + (pb + 2) * 32 + d0);
  float4 g3 = *(const float4*)(Dd + (pb + 3) * 32 + d0);

  for (int i = 0; i < NCHK; i += 4) {
    *(float4*)(P + (pb + i) * 2048 + f) = s;
    s.x = fmaf(s.x, g0.x, p0.x); s.y = fmaf(s.y, g0.y, p0.y);
    s.z = fmaf(s.z, g0.z, p0.z); s.w = fmaf(s.w, g0.w, p0.w);
    if (i + 4 < NCHK) {
      p0 = *(const float4*)(P + (pb + i + 4) * 2048 + f);
      g0 = *(const float4*)(Dd + (pb + i + 4) * 32 + d0);
    }
    *(float4*)(P + (pb + i + 1) * 2048 + f) = s;
    s.x = fmaf(s.x, g1.x, p1.x); s.y = fmaf(s.y, g1.y, p1.y);
    s.z = fmaf(s.z, g1.z, p1.z); s.w = fmaf(s.w, g1.w, p1.w);
    if (i + 5 < NCHK) {
      p1 = *(const float4*)(P + (pb + i + 5) * 2048 + f);
      g1 = *(const float4*)(Dd + (pb + i + 5) * 32 + d0);
    }
    *(float4*)(P + (pb + i + 2) * 2048 + f) = s;
    s.x = fmaf(s.x, g2.x, p2.x); s.y = fmaf(s.y, g2.y, p2.y);
    s.z = fmaf(s.z, g2.z, p2.z); s.w = fmaf(s.w, g2.w, p2.w);
    if (i + 6 < NCHK) {
      p2 = *(const float4*)(P + (pb + i + 6) * 2048 + f);
      g2 = *(const float4*)(Dd + (pb + i + 6) * 32 + d0);
    }
    *(float4*)(P + (pb + i + 3) * 2048 + f) = s;
    s.x = fmaf(s.x, g3.x, p3.x); s.y = fmaf(s.y, g3.y, p3.y);
    s.z = fmaf(s.z, g3.z, p3.z); s.w = fmaf(s.w, g3.w, p3.w);
    if (i + 7 < NCHK) {
      p3 = *(const float4*)(P + (pb + i + 7) * 2048 + f);
      g3 = *(const float4*)(Dd + (pb + i + 7) * 32 + d0);
    }
  }
}

// chunk_out + fused group-norm + gate multiply -> bf16 gated [M][1024]
__global__ __launch_bounds__(256)
void gla_chunk_out(const unsigned short* __restrict__ qkv, const float* __restrict__ lg,
                   const float* __restrict__ S, unsigned short* __restrict__ gated)
{
  __shared__ __align__(16) float Lc[CHK][32];
  __shared__ float Gp[8][32];
  __shared__ __align__(16) unsigned short qb[CHK][40];
  __shared__ __align__(16) unsigned short kd[CHK][40];
  __shared__ __align__(16) unsigned short vT[64][72];
  __shared__ __align__(16) unsigned short ST[64][40];
  __shared__ __align__(16) unsigned short Aq[64][72];
  const int blk = blockIdx.x;
  const int bh = blk >> 6, chunk = blk & (NCHK - 1);
  const int b = bh >> 4, h = bh & 15;
  const int tid = threadIdx.x;
  const int w = tid >> 6, l = tid & 63;
  const size_t rbase = ((size_t)b * Lq + (size_t)chunk * CHK) * QKVS;
  const size_t rowq = rbase + h * 32;
  const size_t rowk = rbase + 512 + h * 32;
  const size_t rowv = rbase + 1024 + h * 64;
  const size_t rowl = ((size_t)b * Lq + (size_t)chunk * CHK) * 512 + h * 32;

  #pragma unroll
  for (int r = 0; r < 2; ++r) {
    int s4 = (tid + 256 * r) * 4;
    int t = s4 >> 5, d0 = s4 & 31;
    *(float4*)&Lc[t][d0] = *(const float4*)(lg + rowl + (size_t)t * 512 + d0);
  }
  __syncthreads();
  {
    const int d = tid & 31, g = tid >> 5;
    float v[8];
    float s = 0.f;
    #pragma unroll
    for (int i = 0; i < 8; ++i) { v[i] = Lc[g * 8 + i][d]; s += v[i]; }
    Gp[g][d] = s;
    __syncthreads();
    float run = 0.f;
    for (int i = 0; i < g; ++i) run += Gp[i][d];
    #pragma unroll
    for (int i = 0; i < 8; ++i) { run += v[i]; Lc[g * 8 + i][d] = run; }
  }
  __syncthreads();
  #pragma unroll
  for (int r = 0; r < 2; ++r) {
    int s4 = (tid + 256 * r) * 4;
    int t = s4 >> 5, d0 = s4 & 31;
    ushort4 kv = *(const ushort4*)(qkv + rowk + (size_t)t * QKVS + d0);
    ushort4 qv = *(const ushort4*)(qkv + rowq + (size_t)t * QKVS + d0);
    float4 lc = *(const float4*)&Lc[t][d0];
    ushort4 ko, qo;
    ko.x = f2bf(bf2f(kv.x) * expf(-lc.x)); qo.x = f2bf(bf2f(qv.x) * expf(lc.x));
    ko.y = f2bf(bf2f(kv.y) * expf(-lc.y)); qo.y = f2bf(bf2f(qv.y) * expf(lc.y));
    ko.z = f2bf(bf2f(kv.z) * expf(-lc.z)); qo.z = f2bf(bf2f(qv.z) * expf(lc.z));
    ko.w = f2bf(bf2f(kv.w) * expf(-lc.w)); qo.w = f2bf(bf2f(qv.w) * expf(lc.w));
    *(ushort4*)&kd[t][d0] = ko;
    *(ushort4*)&qb[t][d0] = qo;
  }
  #pragma unroll
  for (int r = 0; r < 4; ++r) {
    int s4 = (tid + 256 * r) * 4;
    int t = s4 >> 6, e0 = s4 & 63;
    ushort4 vv = *(const ushort4*)(qkv + rowv + (size_t)t * QKVS + e0);
    vT[e0 + 0][t] = vv.x;
    vT[e0 + 1][t] = vv.y;
    vT[e0 + 2][t] = vv.z;
    vT[e0 + 3][t] = vv.w;
  }
  #pragma unroll
  for (int r = 0; r < 2; ++r) {
    int s4 = (tid + 256 * r) * 4;
    int e = s4 >> 5, d0 = s4 & 31;
    float4 f = *(const float4*)(S + (size_t)blk * 2048 + s4);
    ushort4 u = make_ushort4(f2bf(f.x), f2bf(f.y), f2bf(f.z), f2bf(f.w));
    *(ushort4*)&ST[e][d0] = u;
  }
  __syncthreads();

  short8 aQ = *(const short8*)((const char*)&qb[0][0] +
               (16 * w + (l & 15)) * 80 + (l >> 4) * 16);
  const int tl0 = (l >> 4) * 4;
  #pragma unroll
  for (int si = 0; si < 4; ++si) {
    if (si <= w) {
      short8 bK = *(const short8*)((const char*)&kd[0][0] +
                   (16 * si + (l & 15)) * 80 + (l >> 4) * 16);
      f32x4 acc = (f32x4){0.f, 0.f, 0.f, 0.f};
      acc = __builtin_amdgcn_mfma_f32_16x16x32_bf16(aQ, bK, acc, 0, 0, 0);
      #pragma unroll
      for (int j = 0; j < 4; ++j) {
        bool keep = (si < w) || ((l & 15) <= tl0 + j);
        Aq[16 * w + tl0 + j][16 * si + (l & 15)] = keep ? f2bf(acc[j]) : 0;
      }
    } else {
      #pragma unroll
      for (int j = 0; j < 4; ++j)
        Aq[16 * w + tl0 + j][16 * si + (l & 15)] = 0;
    }
  }
  __syncthreads();

  short8 aA0 = *(const short8*)((const char*)&Aq[0][0] +
                (16 * w + (l & 15)) * 144 + (l >> 4) * 16);
  short8 aA1 = *(const short8*)((const char*)&Aq[0][0] +
                (16 * w + (l & 15)) * 144 + 64 + (l >> 4) * 16);
  f32x4 accs[4];
  #pragma unroll
  for (int ej = 0; ej < 4; ++ej) {
    f32x4 acc = (f32x4){0.f, 0.f, 0.f, 0.f};
    short8 bV0 = *(const short8*)((const char*)&vT[0][0] +
                  (16 * ej + (l & 15)) * 144 + (l >> 4) * 16);
    short8 bV1 = *(const short8*)((const char*)&vT[0][0] +
                  (16 * ej + (l & 15)) * 144 + 64 + (l >> 4) * 16);
    short8 bS = *(const short8*)((const char*)&ST[0][0] +
                  (16 * ej + (l & 15)) * 80 + (l >> 4) * 16);
    acc = __builtin_amdgcn_mfma_f32_16x16x32_bf16(aA0, bV0, acc, 0, 0, 0);
    acc = __builtin_amdgcn_mfma_f32_16x16x32_bf16(aA1, bV1, acc, 0, 0, 0);
    acc = __builtin_amdgcn_mfma_f32_16x16x32_bf16(aQ,  bS,  acc, 0, 0, 0);
    accs[ej] = acc;
  }

  float mean[4], rstd[4];
  #pragma unroll
  for (int j = 0; j < 4; ++j) {
    float s  = accs[0][j] + accs[1][j] + accs[2][j] + accs[3][j];
    float q2 = accs[0][j] * accs[0][j] + accs[1][j] * accs[1][j]
             + accs[2][j] * accs[2][j] + accs[3][j] * accs[3][j];
    #pragma unroll
    for (int m = 1; m <= 8; m <<= 1) {
      s  += __shfl_xor(s, m, 64);
      q2 += __shfl_xor(q2, m, 64);
    }
    float mu = s * (1.f / 64.f);
    mean[j] = mu;
    rstd[j] = rsqrtf(q2 * (1.f / 64.f) - mu * mu + kEps);
  }

  const size_t gbase = rbase + 2048 + h * 64;
  const size_t obase = ((size_t)b * Lq + (size_t)chunk * CHK) * 1024 + h * 64;
  #pragma unroll
  for (int ej = 0; ej < 4; ++ej) {
    int e = 16 * ej + (l & 15);
    #pragma unroll
    for (int j = 0; j < 4; ++j) {
      int t = 16 * w + tl0 + j;
      float gate = bf2f(qkv[gbase + (size_t)t * QKVS + e]);
      float y = (accs[ej][j] - mean[j]) * rstd[j];
      gated[obase + (size_t)t * 1024 + e] = f2bf(gate * y);
    }
  }
}

} // namespace

extern "C" void kernel_launch(void* const* d_in, const int* in_sizes, int n_in,
                              void* d_out, int out_size, void* d_ws, size_t ws_size,
                              hipStream_t stream)
{
  (void)in_sizes; (void)n_in; (void)out_size; (void)ws_size;
  const float* x   = (const float*)d_in[0];
  const float* Wq  = (const float*)d_in[1];
  const float* Wk  = (const float*)d_in[2];
  const float* Wg1 = (const float*)d_in[3];
  const float* Wg2 = (const float*)d_in[4];
  const float* Wv  = (const float*)d_in[5];
  const float* Wg  = (const float*)d_in[6];
  const float* bg  = (const float*)d_in[7];
  const float* Wo  = (const float*)d_in[8];

  // workspace: 211.3 MB total
  char* w = (char*)d_ws;
  unsigned short* xh   = (unsigned short*)w; w += (size_t)Mrows * 1024 * 2;
  unsigned short* qkvg = (unsigned short*)w; w += (size_t)Mrows * QKVS * 2;
  float*  lgb = (float*)w;                   w += (size_t)Mrows * 512 * 4;
  float*  t1  = (float*)w;                   w += (size_t)Mrows * 16 * 4;
  float*  Pst = (float*)w;                   w += (size_t)64 * NCHK * 2048 * 4;
  float*  Dd  = (float*)w;                   w += (size_t)64 * NCHK * 32 * 4;
  unsigned short* Wqkvgt = (unsigned short*)w; w += (size_t)QKVS * 1024 * 2;
  unsigned short* Wot    = (unsigned short*)w; w += (size_t)1024 * 1024 * 2;
  unsigned short* gated  = xh;   // alias: xh dead after proj GEMM + gemm_g1

  cvt_bf16<<<2048, 256, 0, stream>>>(x, xh, Mrows * 1024 / 4);
  CvtArgs ca;
  ca.W[0] = Wq;  ca.Wt[0] = Wqkvgt;                        ca.N[0] = 512;  ca.scale[0] = 1.f;    ca.start[0] = 0;   ca.nb[0] = 8;
  ca.W[1] = Wk;  ca.Wt[1] = Wqkvgt + (size_t)512 * 1024;   ca.N[1] = 512;  ca.scale[1] = kScale; ca.start[1] = 128; ca.nb[1] = 8;
  ca.W[2] = Wv;  ca.Wt[2] = Wqkvgt + (size_t)1024 * 1024;  ca.N[2] = 1024; ca.scale[2] = 1.f;    ca.start[2] = 256; ca.nb[2] = 16;
  ca.W[3] = Wg;  ca.Wt[3] = Wqkvgt + (size_t)2048 * 1024;  ca.N[3] = 1024; ca.scale[3] = 1.f;    ca.start[3] = 512; ca.nb[3] = 16;
  ca.W[4] = Wo;  ca.Wt[4] = Wot;                           ca.N[4] = 1024; ca.scale[4] = 1.f;    ca.start[4] = 768; ca.nb[4] = 16;
  cvt_w_all<<<1024, 256, 0, stream>>>(ca);
  // fused q|k|v|gate projection (half-tile ring, counted vmcnt)
  gemm256<2><<<dim3(12, 64), 512, 0, stream>>>(xh, Wqkvgt, bg, qkvg, QKVS);
  gemm_g1<<<Mrows / 16, 256, 0, stream>>>(xh, Wg1, t1);
  gemm_g2<<<(Mrows * 512) / 256, 256, 0, stream>>>(t1, Wg2, lgb);
  // chunked recurrence (MFMA) + fused gnorm/gate epilogue
  gla_chunk_state<<<64 * NCHK, 256, 0, stream>>>(qkvg, lgb, Pst, Dd);
  gla_chain<<<128, 256, 0, stream>>>(Pst, Dd);
  gla_chunk_out<<<64 * NCHK, 256, 0, stream>>>(qkvg, lgb, Pst, gated);
  // output projection (fp32 out)
  gemm256<3><<<dim3(4, 64), 512, 0, stream>>>(gated, Wot, nullptr, d_out, 1024);
}

// Round 18
// 329.978 us; speedup vs baseline: 1.3302x; 1.0028x over previous
//
#include <hip/hip_runtime.h>
#include <cstdint>

namespace {

constexpr int Lq  = 4096;
constexpr int Bq  = 4;
constexpr int H_  = 16;
constexpr int Mrows = Bq * Lq;               // 16384
constexpr int CHK  = 64;
constexpr int NCHK = Lq / CHK;               // 64
constexpr int QKVS = 3072;                   // fused q|k|v|gate row stride
constexpr float kScale = 0.17677669529663687f;  // 32^-0.5
constexpr float kEps   = 1e-5f;

typedef __attribute__((ext_vector_type(8))) short short8;
typedef __attribute__((ext_vector_type(4))) float f32x4;

__device__ __forceinline__ float bf2f(unsigned short u) {
  return __uint_as_float(((unsigned)u) << 16);
}
__device__ __forceinline__ unsigned short f2bf(float f) {
  unsigned u = __float_as_uint(f);
  u += 0x7fffu + ((u >> 16) & 1u);   // RNE
  return (unsigned short)(u >> 16);
}
__device__ __forceinline__ void gload_lds16(const void* g, void* l) {
  __builtin_amdgcn_global_load_lds(
      (const __attribute__((address_space(1))) void*)g,
      (__attribute__((address_space(3))) void*)l, 16, 0, 0);
}

// ---------- x fp32 -> bf16 ----------
__global__ __launch_bounds__(256)
void cvt_bf16(const float* __restrict__ in, unsigned short* __restrict__ out, int n4)
{
  int i = blockIdx.x * 256 + threadIdx.x;
  const int stride = gridDim.x * 256;
  for (; i < n4; i += stride) {
    float4 f = ((const float4*)in)[i];
    ushort4 u = make_ushort4(f2bf(f.x), f2bf(f.y), f2bf(f.z), f2bf(f.w));
    ((ushort4*)out)[i] = u;
  }
}

// ---------- batched W[K,N] fp32 -> Wt[N,K] bf16 (5 weights, 1 dispatch) ----------
struct CvtArgs {
  const float* W[5];
  unsigned short* Wt[5];
  int   N[5];
  float scale[5];
  int   start[5];
  int   nb[5];
};

__global__ __launch_bounds__(256)
void cvt_w_all(CvtArgs a)
{
  __shared__ float T[64][65];
  const int tid = threadIdx.x;
  const int b = blockIdx.x;
  int seg = 0;
  #pragma unroll
  for (int i = 1; i < 5; ++i) seg += (b >= a.start[i]) ? 1 : 0;
  const float* W = a.W[seg];
  unsigned short* Wt = a.Wt[seg];
  const int N = a.N[seg];
  const float scale = a.scale[seg];
  const int lb = b - a.start[seg];
  const int n0 = (lb % a.nb[seg]) * 64;
  const int k0 = (lb / a.nb[seg]) * 64;

  #pragma unroll
  for (int it = 0; it < 4; ++it) {
    int kr = (tid >> 4) + it * 16;
    float4 f = *(const float4*)(W + (size_t)(k0 + kr) * N + n0 + (tid & 15) * 4);
    T[kr][(tid & 15) * 4 + 0] = f.x;
    T[kr][(tid & 15) * 4 + 1] = f.y;
    T[kr][(tid & 15) * 4 + 2] = f.z;
    T[kr][(tid & 15) * 4 + 3] = f.w;
  }
  __syncthreads();
  #pragma unroll
  for (int it = 0; it < 4; ++it) {
    int nr = (tid >> 4) + it * 16;
    int c0 = (tid & 15) * 4;
    ushort4 u = make_ushort4(f2bf(T[c0 + 0][nr] * scale), f2bf(T[c0 + 1][nr] * scale),
                             f2bf(T[c0 + 2][nr] * scale), f2bf(T[c0 + 3][nr] * scale));
    *(ushort4*)(Wt + (size_t)(n0 + nr) * 1024 + k0 + c0) = u;
  }
}

// ==== 256x256 8-wave bf16 GEMM, K=1024: 4-slot half-tile ring, counted vmcnt ====
// Per half-step: vmcnt(8) -> barrier -> issue 4 loads for half h+3 ->
// 12 ds_read -> MFMA (compiler-scheduled fine-grained lgkmcnt interleave;
// no forced drain). Loads ~2.5 half-steps stale at their wait.
// EPI: 2 = silu(x+bias[col-2048]) for col>=2048, store bf16
//      3 = plain, store fp32
template<int EPI>
__global__ __launch_bounds__(512, 1)
void gemm256(const unsigned short* __restrict__ A,
             const unsigned short* __restrict__ Bt,
             const float* __restrict__ bias,
             void* __restrict__ Cout, int N)
{
  __shared__ __align__(16) unsigned short Buf[4][16384];   // 4 x 32 KB
  const int tid = threadIdx.x;
  const int w = tid >> 6, l = tid & 63;
  const int wm = w >> 2, wn = w & 3;

  const int nbx = gridDim.x;
  const int bid = blockIdx.y * nbx + blockIdx.x;
  const int xcd = bid & 7;
  const int idx = bid >> 3;
  const int nsup = idx >> 4;           // 16 = 8 mPanels * 2 ni
  const int rem = idx & 15;
  const int mi = rem >> 1, ni = rem & 1;
  const int m0 = (xcd * 8 + mi) * 256;
  const int n0 = (nsup * 2 + ni) * 256;

  const int srow = tid >> 2;                             // 0..127
  const int scol = ((tid & 3) ^ ((tid >> 3) & 3)) * 8;   // pre-swizzled k8-group
  const unsigned short* gA0 = A  + (size_t)(m0 + srow) * 1024 + scol;
  const unsigned short* gA1 = A  + (size_t)(m0 + 128 + srow) * 1024 + scol;
  const unsigned short* gB0 = Bt + (size_t)(n0 + srow) * 1024 + scol;
  const unsigned short* gB1 = Bt + (size_t)(n0 + 128 + srow) * 1024 + scol;

  const int rbA = wm * 128 + (l & 15);
  const int rbB = wn * 64 + (l & 15);
  const int sw = (((((l & 15) >> 1) & 3) ^ (l >> 4)) << 4);

  f32x4 acc[8][4];
  #pragma unroll
  for (int i = 0; i < 8; ++i)
    #pragma unroll
    for (int j = 0; j < 4; ++j)
      acc[i][j] = (f32x4){0.f, 0.f, 0.f, 0.f};

  // prologue: issue halves 0,1,2 (12 loads in flight)
  #pragma unroll
  for (int h = 0; h < 3; ++h) {
    char* dst = (char*)&Buf[h][0] + w * 1024;
    gload_lds16(gA0, dst);
    gload_lds16(gA1, dst + 8192);
    gload_lds16(gB0, dst + 16384);
    gload_lds16(gB1, dst + 24576);
    gA0 += 32; gA1 += 32; gB0 += 32; gB1 += 32;
  }

  for (int h = 0; h < 32; ++h) {
    if (h < 30)       asm volatile("s_waitcnt vmcnt(8)" ::: "memory");
    else if (h == 30) asm volatile("s_waitcnt vmcnt(4)" ::: "memory");
    else              asm volatile("s_waitcnt vmcnt(0)" ::: "memory");
    __builtin_amdgcn_s_barrier();
    __builtin_amdgcn_sched_barrier(0);

    if (h + 3 < 32) {
      char* dst = (char*)&Buf[(h + 3) & 3][0] + w * 1024;
      gload_lds16(gA0, dst);
      gload_lds16(gA1, dst + 8192);
      gload_lds16(gB0, dst + 16384);
      gload_lds16(gB1, dst + 24576);
      gA0 += 32; gA1 += 32; gB0 += 32; gB1 += 32;
    }

    char* ldsA = (char*)&Buf[h & 3][0];
    char* ldsB = ldsA + 16384;
    short8 av[8], bv[4];
    #pragma unroll
    for (int mf = 0; mf < 8; ++mf)
      av[mf] = *(const short8*)(ldsA + (rbA + mf * 16) * 64 + sw);
    #pragma unroll
    for (int nf = 0; nf < 4; ++nf)
      bv[nf] = *(const short8*)(ldsB + (rbB + nf * 16) * 64 + sw);
    // no forced lgkmcnt drain: compiler interleaves ds_read completion
    // with MFMA issue via fine-grained lgkmcnt.
    __builtin_amdgcn_s_setprio(1);
    #pragma unroll
    for (int mf = 0; mf < 8; ++mf)
      #pragma unroll
      for (int nf = 0; nf < 4; ++nf)
        acc[mf][nf] = __builtin_amdgcn_mfma_f32_16x16x32_bf16(
            av[mf], bv[nf], acc[mf][nf], 0, 0, 0);
    __builtin_amdgcn_s_setprio(0);
  }

  // epilogue
  const int cr = (l >> 4) * 4;
  const int cc = l & 15;
  #pragma unroll
  for (int mf = 0; mf < 8; ++mf) {
    #pragma unroll
    for (int nf = 0; nf < 4; ++nf) {
      int row = m0 + wm * 128 + mf * 16 + cr;
      int col = n0 + wn * 64 + nf * 16 + cc;
      #pragma unroll
      for (int j = 0; j < 4; ++j) {
        float x = acc[mf][nf][j];
        if (EPI == 2) {
          if (col >= 2048) {
            float z = x + bias[col - 2048];
            x = z / (1.f + expf(-z));
          }
        }
        if (EPI == 3)
          ((float*)Cout)[(size_t)(row + j) * N + col] = x;
        else
          ((unsigned short*)Cout)[(size_t)(row + j) * N + col] = f2bf(x);
      }
    }
  }
}

// ---------------- t1 = x_bf16[M,1024] @ Wg1[1024,16] (fp32 acc) ----------------
__global__ __launch_bounds__(256)
void gemm_g1(const unsigned short* __restrict__ x, const float* __restrict__ W1,
             float* __restrict__ t1)
{
  __shared__ float Xs[16][64];
  __shared__ float Ws[64][16];
  const int tid = threadIdx.x;
  const int m0 = blockIdx.x * 16;
  const int mi = tid >> 4, n = tid & 15;
  float acc = 0.f;
  for (int k0 = 0; k0 < 1024; k0 += 64) {
    ushort4 xv = *(const ushort4*)(x + (size_t)(m0 + (tid >> 4)) * 1024 + k0 + (tid & 15) * 4);
    Xs[tid >> 4][(tid & 15) * 4 + 0] = bf2f(xv.x);
    Xs[tid >> 4][(tid & 15) * 4 + 1] = bf2f(xv.y);
    Xs[tid >> 4][(tid & 15) * 4 + 2] = bf2f(xv.z);
    Xs[tid >> 4][(tid & 15) * 4 + 3] = bf2f(xv.w);
    *(float4*)&Ws[tid >> 2][(tid & 3) * 4] =
        *(const float4*)(W1 + (size_t)(k0 + (tid >> 2)) * 16 + (tid & 3) * 4);
    __syncthreads();
    #pragma unroll
    for (int kk = 0; kk < 64; ++kk)
      acc = fmaf(Xs[mi][kk], Ws[kk][n], acc);
    __syncthreads();
  }
  t1[(size_t)(m0 + mi) * 16 + n] = acc;
}

// --------- lg = log_sigmoid(t1 @ Wg2) / 16,  [M, 512] fp32 ---------
__global__ __launch_bounds__(256)
void gemm_g2(const float* __restrict__ t1, const float* __restrict__ W2,
             float* __restrict__ lg)
{
  const int idx = blockIdx.x * 256 + threadIdx.x;
  const int m = idx >> 9, n = idx & 511;
  float acc = 0.f;
  #pragma unroll
  for (int kk = 0; kk < 16; ++kk)
    acc = fmaf(t1[m * 16 + kk], W2[kk * 512 + n], acc);
  float ls = fminf(acc, 0.f) - log1pf(expf(-fabsf(acc)));
  lg[idx] = ls * 0.0625f;
}

// ============ chunked GLA — MFMA version (fused qkvg input) ============
__global__ __launch_bounds__(256)
void gla_chunk_state(const unsigned short* __restrict__ qkv, const float* __restrict__ lg,
                     float* __restrict__ P, float* __restrict__ Dd)
{
  __shared__ __align__(16) float Lc[CHK][32];
  __shared__ float Gp[8][32];
  __shared__ __align__(16) unsigned short kdT[32][72];
  __shared__ __align__(16) unsigned short vT[64][72];
  const int blk = blockIdx.x;
  const int bh = blk >> 6, chunk = blk & (NCHK - 1);
  const int b = bh >> 4, h = bh & 15;
  const int tid = threadIdx.x;
  const int w = tid >> 6, l = tid & 63;
  const size_t rbase = ((size_t)b * Lq + (size_t)chunk * CHK) * QKVS;
  const size_t rowk = rbase + 512 + h * 32;
  const size_t rowv = rbase + 1024 + h * 64;
  const size_t rowl = ((size_t)b * Lq + (size_t)chunk * CHK) * 512 + h * 32;

  #pragma unroll
  for (int r = 0; r < 2; ++r) {
    int s4 = (tid + 256 * r) * 4;
    int t = s4 >> 5, d0 = s4 & 31;
    *(float4*)&Lc[t][d0] = *(const float4*)(lg + rowl + (size_t)t * 512 + d0);
  }
  __syncthreads();
  {
    const int d = tid & 31, g = tid >> 5;
    float v[8];
    float s = 0.f;
    #pragma unroll
    for (int i = 0; i < 8; ++i) { v[i] = Lc[g * 8 + i][d]; s += v[i]; }
    Gp[g][d] = s;
    __syncthreads();
    float run = 0.f;
    for (int i = 0; i < g; ++i) run += Gp[i][d];
    #pragma unroll
    for (int i = 0; i < 8; ++i) { run += v[i]; Lc[g * 8 + i][d] = run; }
  }
  __syncthreads();
  #pragma unroll
  for (int r = 0; r < 2; ++r) {
    int s4 = (tid + 256 * r) * 4;
    int t = s4 >> 5, d0 = s4 & 31;
    ushort4 kv = *(const ushort4*)(qkv + rowk + (size_t)t * QKVS + d0);
    float4 lc = *(const float4*)&Lc[t][d0];
    float4 ls = *(const float4*)&Lc[CHK - 1][d0];
    kdT[d0 + 0][t] = f2bf(bf2f(kv.x) * expf(ls.x - lc.x));
    kdT[d0 + 1][t] = f2bf(bf2f(kv.y) * expf(ls.y - lc.y));
    kdT[d0 + 2][t] = f2bf(bf2f(kv.z) * expf(ls.z - lc.z));
    kdT[d0 + 3][t] = f2bf(bf2f(kv.w) * expf(ls.w - lc.w));
  }
  #pragma unroll
  for (int r = 0; r < 4; ++r) {
    int s4 = (tid + 256 * r) * 4;
    int t = s4 >> 6, e0 = s4 & 63;
    ushort4 vv = *(const ushort4*)(qkv + rowv + (size_t)t * QKVS + e0);
    vT[e0 + 0][t] = vv.x;
    vT[e0 + 1][t] = vv.y;
    vT[e0 + 2][t] = vv.z;
    vT[e0 + 3][t] = vv.w;
  }
  __syncthreads();
  #pragma unroll
  for (int dj = 0; dj < 2; ++dj) {
    f32x4 acc = (f32x4){0.f, 0.f, 0.f, 0.f};
    #pragma unroll
    for (int ks = 0; ks < 2; ++ks) {
      short8 aV = *(const short8*)((const char*)&vT[0][0] +
                    (16 * w + (l & 15)) * 144 + ks * 64 + (l >> 4) * 16);
      short8 bK = *(const short8*)((const char*)&kdT[0][0] +
                    (16 * dj + (l & 15)) * 144 + ks * 64 + (l >> 4) * 16);
      acc = __builtin_amdgcn_mfma_f32_16x16x32_bf16(aV, bK, acc, 0, 0, 0);
    }
    #pragma unroll
    for (int j = 0; j < 4; ++j) {
      int e = 16 * w + (l >> 4) * 4 + j;
      int d = 16 * dj + (l & 15);
      P[(size_t)blk * 2048 + e * 32 + d] = acc[j];
    }
  }
  if (tid < 32) Dd[(size_t)blk * 32 + tid] = expf(Lc[CHK - 1][tid]);
}

// chain over chunks per (bh, e-half); depth-4 prefetched.
__global__ __launch_bounds__(256)
void gla_chain(float* __restrict__ P, const float* __restrict__ Dd)
{
  const int bh = blockIdx.x >> 1, half = blockIdx.x & 1;
  const int tid = threadIdx.x;
  const int f = tid * 4 + half * 1024;
  const int d0 = f & 31;
  const size_t pb = (size_t)bh * NCHK;
  float4 s = {0.f, 0.f, 0.f, 0.f};

  float4 p0 = *(const float4*)(P + (pb + 0) * 2048 + f);
  float4 p1 = *(const float4*)(P + (pb + 1) * 2048 + f);
  float4 p2 = *(const float4*)(P + (pb + 2) * 2048 + f);
  float4 p3 = *(const float4*)(P + (pb + 3) * 2048 + f);
  float4 g0 = *(const float4*)(Dd + (pb + 0) * 32 + d0);
  float4 g1 = *(const float4*)(Dd + (pb + 1) * 32 + d0);
  float4 g2 = *(const float4*)(Dd + (pb + 2) * 32 + d0);
  float4 g3 = *(const float4*)(Dd + (pb + 3) * 32 + d0);

  for (int i = 0; i < NCHK; i += 4) {
    *(float4*)(P + (pb + i) * 2048 + f) = s;
    s.x = fmaf(s.x, g0.x, p0.x); s.y = fmaf(s.y, g0.y, p0.y);
    s.z = fmaf(s.z, g0.z, p0.z); s.w = fmaf(s.w, g0.w, p0.w);
    if (i + 4 < NCHK) {
      p0 = *(const float4*)(P + (pb + i + 4) * 2048 + f);
      g0 = *(const float4*)(Dd + (pb + i + 4) * 32 + d0);
    }
    *(float4*)(P + (pb + i + 1) * 2048 + f) = s;
    s.x = fmaf(s.x, g1.x, p1.x); s.y = fmaf(s.y, g1.y, p1.y);
    s.z = fmaf(s.z, g1.z, p1.z); s.w = fmaf(s.w, g1.w, p1.w);
    if (i + 5 < NCHK) {
      p1 = *(const float4*)(P + (pb + i + 5) * 2048 + f);
      g1 = *(const float4*)(Dd + (pb + i + 5) * 32 + d0);
    }
    *(float4*)(P + (pb + i + 2) * 2048 + f) = s;
    s.x = fmaf(s.x, g2.x, p2.x); s.y = fmaf(s.y, g2.y, p2.y);
    s.z = fmaf(s.z, g2.z, p2.z); s.w = fmaf(s.w, g2.w, p2.w);
    if (i + 6 < NCHK) {
      p2 = *(const float4*)(P + (pb + i + 6) * 2048 + f);
      g2 = *(const float4*)(Dd + (pb + i + 6) * 32 + d0);
    }
    *(float4*)(P + (pb + i + 3) * 2048 + f) = s;
    s.x = fmaf(s.x, g3.x, p3.x); s.y = fmaf(s.y, g3.y, p3.y);
    s.z = fmaf(s.z, g3.z, p3.z); s.w = fmaf(s.w, g3.w, p3.w);
    if (i + 7 < NCHK) {
      p3 = *(const float4*)(P + (pb + i + 7) * 2048 + f);
      g3 = *(const float4*)(Dd + (pb + i + 7) * 32 + d0);
    }
  }
}

// chunk_out + fused group-norm + gate multiply -> bf16 gated [M][1024]
__global__ __launch_bounds__(256)
void gla_chunk_out(const unsigned short* __restrict__ qkv, const float* __restrict__ lg,
                   const float* __restrict__ S, unsigned short* __restrict__ gated)
{
  __shared__ __align__(16) float Lc[CHK][32];
  __shared__ float Gp[8][32];
  __shared__ __align__(16) unsigned short qb[CHK][40];
  __shared__ __align__(16) unsigned short kd[CHK][40];
  __shared__ __align__(16) unsigned short vT[64][72];
  __shared__ __align__(16) unsigned short ST[64][40];
  __shared__ __align__(16) unsigned short Aq[64][72];
  const int blk = blockIdx.x;
  const int bh = blk >> 6, chunk = blk & (NCHK - 1);
  const int b = bh >> 4, h = bh & 15;
  const int tid = threadIdx.x;
  const int w = tid >> 6, l = tid & 63;
  const size_t rbase = ((size_t)b * Lq + (size_t)chunk * CHK) * QKVS;
  const size_t rowq = rbase + h * 32;
  const size_t rowk = rbase + 512 + h * 32;
  const size_t rowv = rbase + 1024 + h * 64;
  const size_t rowl = ((size_t)b * Lq + (size_t)chunk * CHK) * 512 + h * 32;

  #pragma unroll
  for (int r = 0; r < 2; ++r) {
    int s4 = (tid + 256 * r) * 4;
    int t = s4 >> 5, d0 = s4 & 31;
    *(float4*)&Lc[t][d0] = *(const float4*)(lg + rowl + (size_t)t * 512 + d0);
  }
  __syncthreads();
  {
    const int d = tid & 31, g = tid >> 5;
    float v[8];
    float s = 0.f;
    #pragma unroll
    for (int i = 0; i < 8; ++i) { v[i] = Lc[g * 8 + i][d]; s += v[i]; }
    Gp[g][d] = s;
    __syncthreads();
    float run = 0.f;
    for (int i = 0; i < g; ++i) run += Gp[i][d];
    #pragma unroll
    for (int i = 0; i < 8; ++i) { run += v[i]; Lc[g * 8 + i][d] = run; }
  }
  __syncthreads();
  #pragma unroll
  for (int r = 0; r < 2; ++r) {
    int s4 = (tid + 256 * r) * 4;
    int t = s4 >> 5, d0 = s4 & 31;
    ushort4 kv = *(const ushort4*)(qkv + rowk + (size_t)t * QKVS + d0);
    ushort4 qv = *(const ushort4*)(qkv + rowq + (size_t)t * QKVS + d0);
    float4 lc = *(const float4*)&Lc[t][d0];
    ushort4 ko, qo;
    ko.x = f2bf(bf2f(kv.x) * expf(-lc.x)); qo.x = f2bf(bf2f(qv.x) * expf(lc.x));
    ko.y = f2bf(bf2f(kv.y) * expf(-lc.y)); qo.y = f2bf(bf2f(qv.y) * expf(lc.y));
    ko.z = f2bf(bf2f(kv.z) * expf(-lc.z)); qo.z = f2bf(bf2f(qv.z) * expf(lc.z));
    ko.w = f2bf(bf2f(kv.w) * expf(-lc.w)); qo.w = f2bf(bf2f(qv.w) * expf(lc.w));
    *(ushort4*)&kd[t][d0] = ko;
    *(ushort4*)&qb[t][d0] = qo;
  }
  #pragma unroll
  for (int r = 0; r < 4; ++r) {
    int s4 = (tid + 256 * r) * 4;
    int t = s4 >> 6, e0 = s4 & 63;
    ushort4 vv = *(const ushort4*)(qkv + rowv + (size_t)t * QKVS + e0);
    vT[e0 + 0][t] = vv.x;
    vT[e0 + 1][t] = vv.y;
    vT[e0 + 2][t] = vv.z;
    vT[e0 + 3][t] = vv.w;
  }
  #pragma unroll
  for (int r = 0; r < 2; ++r) {
    int s4 = (tid + 256 * r) * 4;
    int e = s4 >> 5, d0 = s4 & 31;
    float4 f = *(const float4*)(S + (size_t)blk * 2048 + s4);
    ushort4 u = make_ushort4(f2bf(f.x), f2bf(f.y), f2bf(f.z), f2bf(f.w));
    *(ushort4*)&ST[e][d0] = u;
  }
  __syncthreads();

  short8 aQ = *(const short8*)((const char*)&qb[0][0] +
               (16 * w + (l & 15)) * 80 + (l >> 4) * 16);
  const int tl0 = (l >> 4) * 4;
  #pragma unroll
  for (int si = 0; si < 4; ++si) {
    if (si <= w) {
      short8 bK = *(const short8*)((const char*)&kd[0][0] +
                   (16 * si + (l & 15)) * 80 + (l >> 4) * 16);
      f32x4 acc = (f32x4){0.f, 0.f, 0.f, 0.f};
      acc = __builtin_amdgcn_mfma_f32_16x16x32_bf16(aQ, bK, acc, 0, 0, 0);
      #pragma unroll
      for (int j = 0; j < 4; ++j) {
        bool keep = (si < w) || ((l & 15) <= tl0 + j);
        Aq[16 * w + tl0 + j][16 * si + (l & 15)] = keep ? f2bf(acc[j]) : 0;
      }
    } else {
      #pragma unroll
      for (int j = 0; j < 4; ++j)
        Aq[16 * w + tl0 + j][16 * si + (l & 15)] = 0;
    }
  }
  __syncthreads();

  short8 aA0 = *(const short8*)((const char*)&Aq[0][0] +
                (16 * w + (l & 15)) * 144 + (l >> 4) * 16);
  short8 aA1 = *(const short8*)((const char*)&Aq[0][0] +
                (16 * w + (l & 15)) * 144 + 64 + (l >> 4) * 16);
  f32x4 accs[4];
  #pragma unroll
  for (int ej = 0; ej < 4; ++ej) {
    f32x4 acc = (f32x4){0.f, 0.f, 0.f, 0.f};
    short8 bV0 = *(const short8*)((const char*)&vT[0][0] +
                  (16 * ej + (l & 15)) * 144 + (l >> 4) * 16);
    short8 bV1 = *(const short8*)((const char*)&vT[0][0] +
                  (16 * ej + (l & 15)) * 144 + 64 + (l >> 4) * 16);
    short8 bS = *(const short8*)((const char*)&ST[0][0] +
                  (16 * ej + (l & 15)) * 80 + (l >> 4) * 16);
    acc = __builtin_amdgcn_mfma_f32_16x16x32_bf16(aA0, bV0, acc, 0, 0, 0);
    acc = __builtin_amdgcn_mfma_f32_16x16x32_bf16(aA1, bV1, acc, 0, 0, 0);
    acc = __builtin_amdgcn_mfma_f32_16x16x32_bf16(aQ,  bS,  acc, 0, 0, 0);
    accs[ej] = acc;
  }

  float mean[4], rstd[4];
  #pragma unroll
  for (int j = 0; j < 4; ++j) {
    float s  = accs[0][j] + accs[1][j] + accs[2][j] + accs[3][j];
    float q2 = accs[0][j] * accs[0][j] + accs[1][j] * accs[1][j]
             + accs[2][j] * accs[2][j] + accs[3][j] * accs[3][j];
    #pragma unroll
    for (int m = 1; m <= 8; m <<= 1) {
      s  += __shfl_xor(s, m, 64);
      q2 += __shfl_xor(q2, m, 64);
    }
    float mu = s * (1.f / 64.f);
    mean[j] = mu;
    rstd[j] = rsqrtf(q2 * (1.f / 64.f) - mu * mu + kEps);
  }

  const size_t gbase = rbase + 2048 + h * 64;
  const size_t obase = ((size_t)b * Lq + (size_t)chunk * CHK) * 1024 + h * 64;
  #pragma unroll
  for (int ej = 0; ej < 4; ++ej) {
    int e = 16 * ej + (l & 15);
    #pragma unroll
    for (int j = 0; j < 4; ++j) {
      int t = 16 * w + tl0 + j;
      float gate = bf2f(qkv[gbase + (size_t)t * QKVS + e]);
      float y = (accs[ej][j] - mean[j]) * rstd[j];
      gated[obase + (size_t)t * 1024 + e] = f2bf(gate * y);
    }
  }
}

} // namespace

extern "C" void kernel_launch(void* const* d_in, const int* in_sizes, int n_in,
                              void* d_out, int out_size, void* d_ws, size_t ws_size,
                              hipStream_t stream)
{
  (void)in_sizes; (void)n_in; (void)out_size; (void)ws_size;
  const float* x   = (const float*)d_in[0];
  const float* Wq  = (const float*)d_in[1];
  const float* Wk  = (const float*)d_in[2];
  const float* Wg1 = (const float*)d_in[3];
  const float* Wg2 = (const float*)d_in[4];
  const float* Wv  = (const float*)d_in[5];
  const float* Wg  = (const float*)d_in[6];
  const float* bg  = (const float*)d_in[7];
  const float* Wo  = (const float*)d_in[8];

  // workspace: 211.3 MB total
  char* w = (char*)d_ws;
  unsigned short* xh   = (unsigned short*)w; w += (size_t)Mrows * 1024 * 2;
  unsigned short* qkvg = (unsigned short*)w; w += (size_t)Mrows * QKVS * 2;
  float*  lgb = (float*)w;                   w += (size_t)Mrows * 512 * 4;
  float*  t1  = (float*)w;                   w += (size_t)Mrows * 16 * 4;
  float*  Pst = (float*)w;                   w += (size_t)64 * NCHK * 2048 * 4;
  float*  Dd  = (float*)w;                   w += (size_t)64 * NCHK * 32 * 4;
  unsigned short* Wqkvgt = (unsigned short*)w; w += (size_t)QKVS * 1024 * 2;
  unsigned short* Wot    = (unsigned short*)w; w += (size_t)1024 * 1024 * 2;
  unsigned short* gated  = xh;   // alias: xh dead after proj GEMM + gemm_g1

  cvt_bf16<<<2048, 256, 0, stream>>>(x, xh, Mrows * 1024 / 4);
  CvtArgs ca;
  ca.W[0] = Wq;  ca.Wt[0] = Wqkvgt;                        ca.N[0] = 512;  ca.scale[0] = 1.f;    ca.start[0] = 0;   ca.nb[0] = 8;
  ca.W[1] = Wk;  ca.Wt[1] = Wqkvgt + (size_t)512 * 1024;   ca.N[1] = 512;  ca.scale[1] = kScale; ca.start[1] = 128; ca.nb[1] = 8;
  ca.W[2] = Wv;  ca.Wt[2] = Wqkvgt + (size_t)1024 * 1024;  ca.N[2] = 1024; ca.scale[2] = 1.f;    ca.start[2] = 256; ca.nb[2] = 16;
  ca.W[3] = Wg;  ca.Wt[3] = Wqkvgt + (size_t)2048 * 1024;  ca.N[3] = 1024; ca.scale[3] = 1.f;    ca.start[3] = 512; ca.nb[3] = 16;
  ca.W[4] = Wo;  ca.Wt[4] = Wot;                           ca.N[4] = 1024; ca.scale[4] = 1.f;    ca.start[4] = 768; ca.nb[4] = 16;
  cvt_w_all<<<1024, 256, 0, stream>>>(ca);
  // fused q|k|v|gate projection (half-tile ring, counted vmcnt)
  gemm256<2><<<dim3(12, 64), 512, 0, stream>>>(xh, Wqkvgt, bg, qkvg, QKVS);
  gemm_g1<<<Mrows / 16, 256, 0, stream>>>(xh, Wg1, t1);
  gemm_g2<<<(Mrows * 512) / 256, 256, 0, stream>>>(t1, Wg2, lgb);
  // chunked recurrence (MFMA) + fused gnorm/gate epilogue
  gla_chunk_state<<<64 * NCHK, 256, 0, stream>>>(qkvg, lgb, Pst, Dd);
  gla_chain<<<128, 256, 0, stream>>>(Pst, Dd);
  gla_chunk_out<<<64 * NCHK, 256, 0, stream>>>(qkvg, lgb, Pst, gated);
  // output projection (fp32 out)
  gemm256<3><<<dim3(4, 64), 512, 0, stream>>>(gated, Wot, nullptr, d_out, 1024);
}